// Round 5
// baseline (332.461 us; speedup 1.0000x reference)
//
#include <hip/hip_runtime.h>
#include <hip/hip_fp16.h>
#include <stdint.h>

typedef unsigned short u16;
typedef unsigned int u32;
typedef __attribute__((ext_vector_type(8))) short bf16x8;
typedef __attribute__((ext_vector_type(4))) short bf16x4;
typedef __attribute__((ext_vector_type(4))) float f32x4;

#define DD 128
#define CAP 64     // Poisson(16): P(deg>64) ~ 1e-20; overflow path still correct
#define STRA 136   // A/C half-tile LDS stride (u16): 272B rows, 16B-aligned
#define STRCF 132  // k6 f32 C-tile stride

__device__ __forceinline__ float bflo(u32 u){ return __uint_as_float(u<<16); }
__device__ __forceinline__ float bfhi(u32 u){ return __uint_as_float(u & 0xffff0000u); }
__device__ __forceinline__ float bf2f(u16 u){ return __uint_as_float(((u32)u)<<16); }
__device__ __forceinline__ u16 f2bf(float f){
  u32 u = __float_as_uint(f);
  return (u16)((u + 0x7fffu + ((u>>16)&1u)) >> 16);   // RNE
}

#define FMA8(g, vv) do { \
    acc[0] += (vv)*bflo((g).x); acc[1] += (vv)*bfhi((g).x); \
    acc[2] += (vv)*bflo((g).y); acc[3] += (vv)*bfhi((g).y); \
    acc[4] += (vv)*bflo((g).z); acc[5] += (vv)*bfhi((g).z); \
    acc[6] += (vv)*bflo((g).w); acc[7] += (vv)*bfhi((g).w); } while(0)

// kU: fused init. (a) zero control region (COMPUTE kernel, never SDMA/memset —
// graph replay ordering), (b) pre-swizzle weights into MFMA B-fragment order,
// (c) build gather table T[r] = [bf16(x_r) (128) | bf16(perb_r) (128)].
__global__ __launch_bounds__(256) void kU_init(
    const float* __restrict__ x, const float* __restrict__ perb,
    const float* __restrict__ W, const float* __restrict__ Wt,
    const float* __restrict__ W1, const float* __restrict__ W2,
    u16* __restrict__ T, u16* __restrict__ Bswz,
    u16* __restrict__ W1swz, u16* __restrict__ W2swz,
    int* __restrict__ deg, float* __restrict__ stats,
    float* __restrict__ gbuf, int N)
{
  int f = blockIdx.x*256 + threadIdx.x;
  if (f < N) deg[f] = 0;
  if (f < 512) stats[f] = 0.f;
  if (f < 64) gbuf[f] = 0.f;   // covers gloss + ovfc (256B block)
  if (f < 65536) {
    int idx = f;
    if (idx < 32768) {
      int j = idx & 7, lane = (idx>>3)&63, nt = (idx>>9)&15, kt = idx>>13;
      int k = kt*32 + (lane>>4)*8 + j, n = nt*16 + (lane&15);
      float v = (n < DD) ? W[k*DD + n] : Wt[k*DD + (n-DD)];
      Bswz[idx] = f2bf(v);
    } else {
      int t = idx - 32768;
      int which = t >> 14; t &= 16383;
      int j = t & 7, lane = (t>>3)&63, nt = (t>>9)&7, kt = (t>>12)&3;
      int k = kt*32 + (lane>>4)*8 + j, n = nt*16 + (lane&15);
      const float* __restrict__ src = which ? W2 : W1;
      u16* __restrict__ dst = which ? W2swz : W1swz;
      dst[t] = f2bf(src[k*DD + n]);
    }
  }
  if (f < N*32) {
    int r = f >> 5, c8 = f & 31;
    const float* src = (c8 < 16) ? (x + (size_t)r*DD + c8*8)
                                 : (perb + (size_t)r*DD + (c8-16)*8);
    float4 a = *(const float4*)src;
    float4 bq = *(const float4*)(src + 4);
    bf16x8 o;
    o[0]=(short)f2bf(a.x); o[1]=(short)f2bf(a.y); o[2]=(short)f2bf(a.z); o[3]=(short)f2bf(a.w);
    o[4]=(short)f2bf(bq.x); o[5]=(short)f2bf(bq.y); o[6]=(short)f2bf(bq.z); o[7]=(short)f2bf(bq.w);
    *(bf16x8*)(T + (size_t)r*256 + c8*8) = o;
  }
}

// K2: bucket edges by destination row. Packed 4B/edge: col:u16 | val:f16
// (N<65536; f16 rel err 5e-4 -> negligible).
__global__ __launch_bounds__(256) void k2_bucket(
    const int* __restrict__ row, const int* __restrict__ col,
    const float* __restrict__ val, int E, int* __restrict__ deg,
    u32* __restrict__ perm, int* __restrict__ ovfc, int* __restrict__ ovf)
{
  int e = blockIdx.x*256 + threadIdx.x;
  if (e >= E) return;
  int r = row[e];
  int slot = atomicAdd(&deg[r], 1);
  if (slot < CAP) {
    u32 pk = (u32)(col[e] & 0xffff)
           | ((u32)__half_as_ushort(__float2half(val[e])) << 16);
    perm[(size_t)r*CAP + slot] = pk;
  }
  else { int oi = atomicAdd(ovfc, 1); if (oi < 4096) ovf[oi] = e; }
}

// K3: one wave per row. dwordx4 gathers: 32 lanes cover one 512B T-row,
// two wave-halves process even/odd edges. Bound by random-gather memory
// throughput (R0 vs R1: halving VMEM instrs left dur unchanged).
__global__ __launch_bounds__(256) void k3_spmm(
    const u32* __restrict__ perm, const int* __restrict__ deg,
    const u16* __restrict__ T, u16* __restrict__ T2, int N)
{
  int row = blockIdx.x*4 + (threadIdx.x >> 6);
  int l = threadIdx.x & 63;
  if (row >= N) return;
  int dg = deg[row];
  dg = dg < 0 ? 0 : (dg > CAP ? CAP : dg);       // defensive clamp
  const int half = l >> 5, hl = l & 31;
  const int eoff = hl * 8;                        // elem offset in 256-wide T row
  float acc[8] = {0.f,0.f,0.f,0.f,0.f,0.f,0.f,0.f};
  for (int base = 0; base < dg; base += 64) {
    u32 pk = 0;                                   // pad: c=0, v=0 (harmless gather)
    if (base + l < dg) pk = perm[(size_t)row*CAP + base + l];
    int mm = dg - base; if (mm > 64) mm = 64;
    int kmax = (mm + 1) & ~1;                     // round up to even (pad v=0)
    int j = 0;
    for (; j + 8 <= kmax; j += 8) {
      u32 p0 = (u32)__shfl((int)pk, j + half);
      u32 p1 = (u32)__shfl((int)pk, j + 2 + half);
      u32 p2 = (u32)__shfl((int)pk, j + 4 + half);
      u32 p3 = (u32)__shfl((int)pk, j + 6 + half);
      int c0 = p0 & 0xffff; c0 = (c0 < N) ? c0 : 0;
      int c1 = p1 & 0xffff; c1 = (c1 < N) ? c1 : 0;
      int c2 = p2 & 0xffff; c2 = (c2 < N) ? c2 : 0;
      int c3 = p3 & 0xffff; c3 = (c3 < N) ? c3 : 0;
      float v0 = __half2float(__ushort_as_half((u16)(p0 >> 16)));
      float v1 = __half2float(__ushort_as_half((u16)(p1 >> 16)));
      float v2 = __half2float(__ushort_as_half((u16)(p2 >> 16)));
      float v3 = __half2float(__ushort_as_half((u16)(p3 >> 16)));
      uint4 g0 = *(const uint4*)(T + (size_t)c0*256 + eoff);
      uint4 g1 = *(const uint4*)(T + (size_t)c1*256 + eoff);
      uint4 g2 = *(const uint4*)(T + (size_t)c2*256 + eoff);
      uint4 g3 = *(const uint4*)(T + (size_t)c3*256 + eoff);
      FMA8(g0, v0); FMA8(g1, v1); FMA8(g2, v2); FMA8(g3, v3);
    }
    for (; j < kmax; j += 2) {
      u32 p0 = (u32)__shfl((int)pk, j + half);
      int c0 = p0 & 0xffff; c0 = (c0 < N) ? c0 : 0;
      float v0 = __half2float(__ushort_as_half((u16)(p0 >> 16)));
      uint4 g0 = *(const uint4*)(T + (size_t)c0*256 + eoff);
      FMA8(g0, v0);
    }
  }
  // combine even/odd-edge partials across halves
  #pragma unroll
  for (int i = 0; i < 8; ++i) acc[i] += __shfl_xor(acc[i], 32);
  // hl<16 holds x-part elems (aggx1), hl>=16 holds perb-part elems;
  // aggx2[e] = aggx1[e] + aggp[e]: fetch partner-x from lane hl-16.
  int sel = (hl >= 16) ? (hl - 16) : hl;
  bf16x8 ob;
  #pragma unroll
  for (int i = 0; i < 8; ++i) {
    float xv = __shfl(acc[i], sel);
    float o = (hl < 16) ? acc[i] : (xv + acc[i]);
    ob[i] = (short)f2bf(o);
  }
  if (half == 0)
    *(bf16x8*)(T2 + (size_t)row*256 + hl*8) = ob;   // 32 lanes x 16B = 512B row
}

// K3b: overflow fallback (expected empty) — serial RMW on T2 (raw edges).
__global__ __launch_bounds__(256) void k3b_ovf(
    const int* __restrict__ rowI, const int* __restrict__ colI,
    const float* __restrict__ val, const int* __restrict__ ovfc,
    const int* __restrict__ ovf, const u16* __restrict__ T,
    u16* __restrict__ T2)
{
  int n = *ovfc; if (n > 4096) n = 4096;
  for (int i = 0; i < n; ++i) {
    int e = ovf[i];
    int r = rowI[e], c = colI[e];
    float v = val[e];
    int d = threadIdx.x;           // 256 threads cover the 256-wide row
    int dl = d & 127;
    float add = v * bf2f(T[(size_t)c*256 + dl]);
    if (d >= 128) add += v * bf2f(T[(size_t)c*256 + 128 + dl]);
    u16* p = &T2[(size_t)r*256 + d];
    *p = f2bf(bf2f(*p) + add);
  }
}

// K4 (fused k4+k5, R5 restructure): stage1 split into two N-half passes so the
// C-tile is HALF-width (64x136 u16 = 17.4KB). LDS 51.2->34.8KB (4 blocks/CU);
// one shared f32x4 acc[8] for passA/passB/stage2 (96->32 AGPRs).
//   passA: [aggx1;aggx2] @ [W|Wt] cols 128-255 -> Ct = [s1|s3] -> AGGb
//   passB: cols 0-127 + bias -> Ct = [s0|s2+b] -> embed; stage2 A-operand
//   stage2: P = Ct @ W1 + b1 -> BN partials + Px/Py (bf16 tile in Ct)
// Numerics bit-identical to R4 fused k4.
__global__ __launch_bounds__(256, 4) void k4_gemm(
    const u16* __restrict__ T2, const u16* __restrict__ Bswz,
    const u16* __restrict__ W1swz,
    const float* __restrict__ b, const float* __restrict__ bt,
    const float* __restrict__ b1, const u16* __restrict__ T,
    u16* __restrict__ AGGb, float* __restrict__ outE,
    u16* __restrict__ Px, u16* __restrict__ Py,
    float* __restrict__ partial, int N, int NB)
{
  __shared__ __align__(16) u16 As1[64*STRA];   // 17408B; later red (f32[1024])
  __shared__ __align__(16) u16 Ct[64*STRA];    // 17408B half C-tile (u16/bf16)
  const int tid = threadIdx.x;
  const int r0 = blockIdx.x * 32;
  // ---- load A (64 rows: 0-31 = aggx1, 32-63 = aggx2) ----
  #pragma unroll
  for (int i = 0; i < 4; ++i) {
    int f = tid + 256*i;            // 1024 chunks: 64 A-rows x 16 chunks of 8
    int row = f >> 4, c8 = f & 15;
    int r = r0 + (row & 31);
    bf16x8 ch = {0,0,0,0,0,0,0,0};
    if (r < N) ch = *(const bf16x8*)(T2 + (size_t)r*256 + (row>>5)*128 + c8*8);
    *(bf16x8*)&As1[row*STRA + c8*8] = ch;
  }
  __syncthreads();                                        // (1)
  const int w = tid >> 6, l = tid & 63;
  const int m = l & 15, q = l >> 4;
  const int arow = w*16 + m;
  f32x4 acc[8];
  // ---- stage1 pass A: global cols 128..255 ([s1|s3]) ----
  #pragma unroll
  for (int nt = 0; nt < 8; ++nt) acc[nt] = (f32x4){0.f,0.f,0.f,0.f};
  #pragma unroll
  for (int kt = 0; kt < 4; ++kt) {
    bf16x8 af = *(const bf16x8*)&As1[arow*STRA + kt*32 + q*8];
    #pragma unroll
    for (int nt = 0; nt < 8; ++nt) {
      bf16x8 bfr = *(const bf16x8*)(Bswz + ((size_t)(kt*16 + 8 + nt)*64 + l)*8);
      acc[nt] = __builtin_amdgcn_mfma_f32_16x16x32_bf16(af, bfr, acc[nt], 0, 0, 0);
    }
  }
  #pragma unroll
  for (int nt = 0; nt < 8; ++nt) {
    float bv = bt[nt*16 + m];                             // col = 128+nt*16+m
    #pragma unroll
    for (int i = 0; i < 4; ++i)
      Ct[(w*16 + q*4 + i)*STRA + nt*16 + m] = f2bf(acc[nt][i] + bv);
  }
  __syncthreads();                                        // (2)
  // ---- AGGb write: [s1|s3] (rows<32 -> s1 @0, rows>=32 -> s3 @128) ----
  {
    const int ar = tid >> 2, p = tid & 3;
    const int src = r0 + (ar & 31);
    if (src < N) {
      u16* dp = AGGb + (size_t)src*256 + (ar>>5)*128 + p*32;
      const u16* sp = &Ct[ar*STRA + p*32];
      #pragma unroll
      for (int i = 0; i < 4; ++i)
        *(bf16x8*)(dp + i*8) = *(const bf16x8*)(sp + i*8);
    }
  }
  __syncthreads();                                        // (3) Ct reads done
  // ---- stage1 pass B: global cols 0..127 ([s0|s2] + bias) ----
  #pragma unroll
  for (int nt = 0; nt < 8; ++nt) acc[nt] = (f32x4){0.f,0.f,0.f,0.f};
  #pragma unroll
  for (int kt = 0; kt < 4; ++kt) {
    bf16x8 af = *(const bf16x8*)&As1[arow*STRA + kt*32 + q*8];
    #pragma unroll
    for (int nt = 0; nt < 8; ++nt) {
      bf16x8 bfr = *(const bf16x8*)(Bswz + ((size_t)(kt*16 + nt)*64 + l)*8);
      acc[nt] = __builtin_amdgcn_mfma_f32_16x16x32_bf16(af, bfr, acc[nt], 0, 0, 0);
    }
  }
  #pragma unroll
  for (int nt = 0; nt < 8; ++nt) {
    float bv = b[nt*16 + m];
    #pragma unroll
    for (int i = 0; i < 4; ++i)
      Ct[(w*16 + q*4 + i)*STRA + nt*16 + m] = f2bf(acc[nt][i] + bv);
  }
  __syncthreads();                                        // (4)
  // ---- embed = x + perb + s2 (Ct rows 32-63, bias incl.); x,perb from T ----
  #pragma unroll
  for (int i = 0; i < 2; ++i) {
    int f = tid + 256*i;            // 512 chunks: 32 rows x 16 chunks of 8
    int rr = f >> 4, c8 = f & 15;
    int src = r0 + rr;
    if (src < N) {
      const u16* cp = &Ct[(32+rr)*STRA + c8*8];
      bf16x8 xv = *(const bf16x8*)(T + (size_t)src*256 + c8*8);
      bf16x8 pv = *(const bf16x8*)(T + (size_t)src*256 + 128 + c8*8);
      bf16x8 cv = *(const bf16x8*)cp;
      float4 e0, e1;
      e0.x = bf2f((u16)xv[0])+bf2f((u16)pv[0])+bf2f((u16)cv[0]);
      e0.y = bf2f((u16)xv[1])+bf2f((u16)pv[1])+bf2f((u16)cv[1]);
      e0.z = bf2f((u16)xv[2])+bf2f((u16)pv[2])+bf2f((u16)cv[2]);
      e0.w = bf2f((u16)xv[3])+bf2f((u16)pv[3])+bf2f((u16)cv[3]);
      e1.x = bf2f((u16)xv[4])+bf2f((u16)pv[4])+bf2f((u16)cv[4]);
      e1.y = bf2f((u16)xv[5])+bf2f((u16)pv[5])+bf2f((u16)cv[5]);
      e1.z = bf2f((u16)xv[6])+bf2f((u16)pv[6])+bf2f((u16)cv[6]);
      e1.w = bf2f((u16)xv[7])+bf2f((u16)pv[7])+bf2f((u16)cv[7]);
      float* er = outE + (size_t)src*DD + c8*8;
      *(float4*)er = e0;
      *(float4*)(er+4) = e1;
    }
  }
  // ---- stage2 MFMA: P = Ct[:, 0:128] @ W1 (A read in-place, stride STRA) ----
  #pragma unroll
  for (int nt = 0; nt < 8; ++nt) acc[nt] = (f32x4){0.f,0.f,0.f,0.f};
  #pragma unroll
  for (int kt = 0; kt < 4; ++kt) {
    bf16x8 af = *(const bf16x8*)&Ct[arow*STRA + kt*32 + q*8];
    #pragma unroll
    for (int nt = 0; nt < 8; ++nt) {
      bf16x8 bfr = *(const bf16x8*)(W1swz + ((size_t)(kt*8+nt)*64 + l)*8);
      acc[nt] = __builtin_amdgcn_mfma_f32_16x16x32_bf16(af, bfr, acc[nt], 0, 0, 0);
    }
  }
  // ---- b1 + validity + BN partial sums (red lives in As1 region; As1 dead) ----
  float* red = (float*)As1;         // [type(2)][wave(4)*128 + col] = 4KB
  #pragma unroll
  for (int nt = 0; nt < 8; ++nt) {
    float bv = b1[nt*16 + m];
    float sum = 0.f, sq = 0.f;
    #pragma unroll
    for (int i = 0; i < 4; ++i) {
      int src = r0 + ((w*16 + q*4 + i) & 31);
      if (src < N) acc[nt][i] += bv; else acc[nt][i] = 0.f;
      sum += acc[nt][i]; sq += acc[nt][i]*acc[nt][i];
    }
    sum += __shfl_xor(sum, 16); sum += __shfl_xor(sum, 32);
    sq  += __shfl_xor(sq, 16);  sq  += __shfl_xor(sq, 32);
    if (l < 16) {
      red[      w*128 + nt*16 + l] = sum;
      red[512 + w*128 + nt*16 + l] = sq;
    }
  }
  __syncthreads();                                        // (5)
  {
    // waves 0,1 = rows 0-31 = seg0 (Px); waves 2,3 = rows 32-63 = seg1 (Py)
    int type = tid >> 7, col = tid & 127;
    float v0 = red[type*512 +   0 + col] + red[type*512 + 128 + col];
    float v1 = red[type*512 + 256 + col] + red[type*512 + 384 + col];
    partial[((size_t)0*NB + blockIdx.x)*256 + tid] = v0;
    partial[((size_t)1*NB + blockIdx.x)*256 + tid] = v1;
  }
  // ---- P-tile (bf16) into Ct: all Ct reads completed before sync(5) ----
  #pragma unroll
  for (int nt = 0; nt < 8; ++nt)
    #pragma unroll
    for (int i = 0; i < 4; ++i)
      Ct[(w*16 + q*4 + i)*STRA + nt*16 + m] = f2bf(acc[nt][i]);
  __syncthreads();                                        // (6)
  // ---- P write: rows 0-31 -> Px, rows 32-63 -> Py ----
  {
    const int ar = tid >> 2, p = tid & 3;
    const int src = r0 + (ar & 31);
    if (src < N) {
      const u16* sp = &Ct[ar*STRA + p*32];
      u16* dp = ((ar >> 5) ? Py : Px) + (size_t)src*DD + p*32;
      #pragma unroll
      for (int i = 0; i < 4; ++i)
        *(bf16x8*)(dp + i*8) = *(const bf16x8*)(sp + i*8);
    }
  }
}

// K5b: reduce per-block partials into stats (few atomics).
__global__ __launch_bounds__(256) void k5b_stats(
    const float* __restrict__ partial, float* __restrict__ stats, int nb)
{
  int seg = blockIdx.y, chunk = blockIdx.x, t = threadIdx.x;
  int per = (nb + gridDim.x - 1) / gridDim.x;
  int lo = chunk*per, hi = lo+per; if (hi > nb) hi = nb;
  float s = 0.f;
  const float* p = partial + (size_t)seg*nb*256;
  for (int i = lo; i < hi; ++i) s += p[(size_t)i*256 + t];
  atomicAdd(&stats[seg*256 + t], s);
}

// K6: BN+PReLU (bf16 P) -> MFMA GEMM2 (+b2) -> parallel per-row BYOL cosine ->
// 1 atomic/block. NO device fence (R1 lesson). AGGb [s1|s3] 256 u16/row:
// seg0 target = s3 (off 128), seg1 target = s1 (off 0).
__global__ __launch_bounds__(256) void k6_gemm_loss(
    const u16* __restrict__ Px, const u16* __restrict__ Py,
    const u16* __restrict__ AGGb, const float* __restrict__ stats,
    const float* __restrict__ gamma, const float* __restrict__ beta,
    const float* __restrict__ aP, const u16* __restrict__ W2swz,
    const float* __restrict__ b2, float* __restrict__ gloss, int N)
{
  __shared__ __align__(16) float Cs[64*STRCF];   // 33792B; aliased as As (17408B)
  u16* As = (u16*)Cs;
  __shared__ float s1s[128], s2s[128];
  __shared__ float gred[4];
  const int tid = threadIdx.x;
  const int seg = blockIdx.y;
  const u16* __restrict__ P = seg ? Py : Px;
  const int toff = seg ? 0 : 128;
  const float invN = 1.f / (float)N;
  if (tid < 128) {
    float mu = stats[seg*256 + tid] * invN;
    float var = stats[seg*256 + 128 + tid] * invN - mu*mu;
    float rstd = rsqrtf(var + 1e-5f);
    float s1 = rstd * gamma[tid];
    s1s[tid] = s1;
    s2s[tid] = beta[tid] - mu*s1;
  }
  const float alpha = aP[0];
  const int r0 = blockIdx.x * 64;
  __syncthreads();
  #pragma unroll
  for (int i = 0; i < 4; ++i) {
    int f = tid + 256*i;
    int row = f >> 4, c8 = f & 15;
    int r = r0 + row;
    bf16x8 ch = {0,0,0,0,0,0,0,0};
    if (r < N) ch = *(const bf16x8*)(P + (size_t)r*DD + c8*8);
    bf16x8 a;
    #pragma unroll
    for (int t2 = 0; t2 < 8; ++t2) {
      int colc = c8*8 + t2;
      float hv = bf2f((u16)ch[t2]);
      float hn = hv*s1s[colc] + s2s[colc];
      hn = hn >= 0.f ? hn : alpha*hn;
      a[t2] = (short)f2bf(hn);
    }
    *(bf16x8*)&As[row*STRA + c8*8] = a;
  }
  __syncthreads();
  const int w = tid >> 6, l = tid & 63;
  const int m = l & 15, q = l >> 4;
  f32x4 acc[8];
  #pragma unroll
  for (int nt = 0; nt < 8; ++nt) acc[nt] = (f32x4){0.f,0.f,0.f,0.f};
  const int arow = w*16 + m;
  #pragma unroll
  for (int kt = 0; kt < 4; ++kt) {
    bf16x8 af = *(const bf16x8*)&As[arow*STRA + kt*32 + q*8];
    #pragma unroll
    for (int nt = 0; nt < 8; ++nt) {
      bf16x8 bfr = *(const bf16x8*)(W2swz + ((size_t)(kt*8+nt)*64 + l)*8);
      acc[nt] = __builtin_amdgcn_mfma_f32_16x16x32_bf16(af, bfr, acc[nt], 0, 0, 0);
    }
  }
  __syncthreads();                  // As dead; Cs writes follow (aliased)
  #pragma unroll
  for (int nt = 0; nt < 8; ++nt) {
    float bv = b2[nt*16 + m];
    #pragma unroll
    for (int i = 0; i < 4; ++i)
      Cs[(w*16 + q*4 + i)*STRCF + nt*16 + m] = acc[nt][i] + bv;
  }
  __syncthreads();
  // Parallel BYOL cosine: 4 lanes per row; xor1+xor2 completes row sums;
  // xor4..32 sums 16 distinct rows once per qq-group (no /4 — R2 lesson).
  {
    const int rt = tid >> 2, qq = tid & 3;
    const int r = r0 + rt;
    float pp = 0.f, tt = 0.f, pt = 0.f;
    if (r < N) {
      const float* prow = &Cs[rt*STRCF + qq*32];
      const u16* trow = AGGb + (size_t)r*256 + toff + qq*32;
      #pragma unroll
      for (int i = 0; i < 4; ++i) {
        float4 pa = *(const float4*)(prow + i*8);
        float4 pb = *(const float4*)(prow + i*8 + 4);
        uint4 twv = *(const uint4*)(trow + i*8);
        float t0=bflo(twv.x), t1=bfhi(twv.x), t2=bflo(twv.y), t3=bfhi(twv.y);
        float t4=bflo(twv.z), t5=bfhi(twv.z), t6=bflo(twv.w), t7=bfhi(twv.w);
        pp += pa.x*pa.x + pa.y*pa.y + pa.z*pa.z + pa.w*pa.w
            + pb.x*pb.x + pb.y*pb.y + pb.z*pb.z + pb.w*pb.w;
        tt += t0*t0 + t1*t1 + t2*t2 + t3*t3 + t4*t4 + t5*t5 + t6*t6 + t7*t7;
        pt += pa.x*t0 + pa.y*t1 + pa.z*t2 + pa.w*t3
            + pb.x*t4 + pb.y*t5 + pb.z*t6 + pb.w*t7;
      }
    }
    pp += __shfl_xor(pp, 1); pp += __shfl_xor(pp, 2);
    tt += __shfl_xor(tt, 1); tt += __shfl_xor(tt, 2);
    pt += __shfl_xor(pt, 1); pt += __shfl_xor(pt, 2);
    float lsum = (r < N) ? (2.f - 2.f * pt * rsqrtf(pp * tt)) : 0.f;
    lsum += __shfl_xor(lsum, 4);  lsum += __shfl_xor(lsum, 8);
    lsum += __shfl_xor(lsum, 16); lsum += __shfl_xor(lsum, 32);
    if (l == 0) gred[w] = lsum;
  }
  __syncthreads();
  if (tid == 0) atomicAdd(gloss, gred[0]+gred[1]+gred[2]+gred[3]);
}

__global__ void k7_loss(const float* __restrict__ gloss, float* __restrict__ out, int N, int total)
{
  out[total] = gloss[0] / (float)N;
}

extern "C" void kernel_launch(void* const* d_in, const int* in_sizes, int n_in,
                              void* d_out, int out_size, void* d_ws, size_t ws_size,
                              hipStream_t stream)
{
  const float* x    = (const float*)d_in[0];
  const float* perb = (const float*)d_in[1];
  const int*   erow = (const int*)d_in[2];
  const int*   ecol = (const int*)d_in[3];
  const float* eval_= (const float*)d_in[4];
  const float* W    = (const float*)d_in[5];
  const float* b    = (const float*)d_in[6];
  const float* Wt   = (const float*)d_in[7];
  const float* bt   = (const float*)d_in[8];
  const float* W1   = (const float*)d_in[9];
  const float* b1   = (const float*)d_in[10];
  const float* gam  = (const float*)d_in[11];
  const float* bet  = (const float*)d_in[12];
  const float* aP   = (const float*)d_in[13];
  const float* W2   = (const float*)d_in[14];
  const float* b2   = (const float*)d_in[15];
  const int N = in_sizes[0] / DD;
  const int E = in_sizes[2];
  const int NB4 = (N + 31)/32;
  const int NB5 = (N + 63)/64;

  char* ws = (char*)d_ws;
  size_t off = 0;
  auto alloc = [&](size_t bytes) -> void* {
    void* p = ws + off;
    off += (bytes + 255) & ~(size_t)255;
    return p;
  };
  u16*   AGGb = (u16*)  alloc((size_t)N*256*sizeof(u16));   // 25.6 MB [s1|s3]
  u16*   T    = (u16*)  alloc((size_t)N*256*sizeof(u16));   // 25.6 MB
  u16*   T2   = (u16*)  alloc((size_t)N*256*sizeof(u16));   // 25.6 MB
  u16*   Px   = (u16*)  alloc((size_t)N*DD*sizeof(u16));    // 12.8 MB
  u16*   Py   = (u16*)  alloc((size_t)N*DD*sizeof(u16));    // 12.8 MB
  int*   deg  = (int*)  alloc((size_t)N*sizeof(int));
  float* stats= (float*)alloc(512*sizeof(float));
  float* gloss= (float*)alloc(256);
  int*   ovfc = (int*)((char*)gloss + 64);
  u32*   perm = (u32*)  alloc((size_t)N*CAP*sizeof(u32));   // 12.8 MB packed
  int*   ovf  = (int*)  alloc(4096*sizeof(int));
  u16*   Bswz = (u16*)  alloc(32768*sizeof(u16));
  u16*   W1swz= (u16*)  alloc(16384*sizeof(u16));
  u16*   W2swz= (u16*)  alloc(16384*sizeof(u16));
  float* partial = (float*)alloc((size_t)2*NB4*256*sizeof(float)); // 3.2 MB
  if (ws_size < off) return;

  kU_init<<<(N*32 + 255)/256, 256, 0, stream>>>(x, perb, W, Wt, W1, W2,
                                                T, Bswz, W1swz, W2swz,
                                                deg, stats, gloss, N);
  k2_bucket<<<(E + 255)/256, 256, 0, stream>>>(erow, ecol, eval_, E, deg, perm, ovfc, ovf);
  k3_spmm<<<(N + 3)/4, 256, 0, stream>>>(perm, deg, T, T2, N);
  k3b_ovf<<<1, 256, 0, stream>>>(erow, ecol, eval_, ovfc, ovf, T, T2);
  k4_gemm<<<NB4, 256, 0, stream>>>(T2, Bswz, W1swz, b, bt, b1, T,
                                   AGGb, (float*)d_out, Px, Py, partial, N, NB4);
  k5b_stats<<<dim3(16, 2), 256, 0, stream>>>(partial, stats, NB4);
  k6_gemm_loss<<<dim3(NB5, 2), 256, 0, stream>>>(Px, Py, AGGb, stats, gam, bet, aP,
                                                 W2swz, b2, gloss, N);
  k7_loss<<<1, 1, 0, stream>>>(gloss, (float*)d_out, N, N*DD);
}

// Round 6
// 313.820 us; speedup vs baseline: 1.0594x; 1.0594x over previous
//
#include <hip/hip_runtime.h>
#include <hip/hip_fp16.h>
#include <stdint.h>

typedef unsigned short u16;
typedef unsigned int u32;
typedef unsigned char u8;
typedef __attribute__((ext_vector_type(8))) short bf16x8;
typedef __attribute__((ext_vector_type(4))) short bf16x4;
typedef __attribute__((ext_vector_type(4))) float f32x4;

#define DD 128
#define CAP 64     // Poisson(16): P(deg>64) ~ 1e-20; overflow path still correct
#define STRA 136   // A/C half-tile LDS stride (u16): 272B rows, 16B-aligned
#define STRCF 132  // k6 f32 C-tile stride
#define PSC 256.f  // perb int8 scale: q = rint(perb*256), |err| <= 0.002
#define IPSC (1.f/256.f)

__device__ __forceinline__ float bflo(u32 u){ return __uint_as_float(u<<16); }
__device__ __forceinline__ float bfhi(u32 u){ return __uint_as_float(u & 0xffff0000u); }
__device__ __forceinline__ float bf2f(u16 u){ return __uint_as_float(((u32)u)<<16); }
__device__ __forceinline__ u16 f2bf(float f){
  u32 u = __float_as_uint(f);
  return (u16)((u + 0x7fffu + ((u>>16)&1u)) >> 16);   // RNE
}

// Tg row (384B): 32 chunks of 12B; chunk hl = [4x bf16 x (8B) | 4x int8 perb (4B)]
// for elems 4hl..4hl+3. 25% fewer gather bytes than the old 512B [x|perb] row.
#define FMAXP(g, vv, vqv) do { \
    ax[0] += (vv)*bflo((g).x); ax[1] += (vv)*bfhi((g).x); \
    ax[2] += (vv)*bflo((g).y); ax[3] += (vv)*bfhi((g).y); \
    int d_ = (int)(g).z; \
    ap[0] += (vqv)*(float)(signed char)(d_); \
    ap[1] += (vqv)*(float)(signed char)(d_>>8); \
    ap[2] += (vqv)*(float)(signed char)(d_>>16); \
    ap[3] += (vqv)*(float)(d_>>24); } while(0)

// kU: fused init. (a) zero control region (COMPUTE kernel, never SDMA/memset —
// graph replay ordering), (b) pre-swizzle weights into MFMA B-fragment order,
// (c) build gather table Tg (bf16 x + int8 perb, 384B/row).
__global__ __launch_bounds__(256) void kU_init(
    const float* __restrict__ x, const float* __restrict__ perb,
    const float* __restrict__ W, const float* __restrict__ Wt,
    const float* __restrict__ W1, const float* __restrict__ W2,
    u8* __restrict__ Tg, u16* __restrict__ Bswz,
    u16* __restrict__ W1swz, u16* __restrict__ W2swz,
    int* __restrict__ deg, float* __restrict__ stats,
    float* __restrict__ gbuf, int N)
{
  int f = blockIdx.x*256 + threadIdx.x;
  if (f < N) deg[f] = 0;
  if (f < 512) stats[f] = 0.f;
  if (f < 64) gbuf[f] = 0.f;   // covers gloss + ovfc (256B block)
  if (f < 65536) {
    int idx = f;
    if (idx < 32768) {
      int j = idx & 7, lane = (idx>>3)&63, nt = (idx>>9)&15, kt = idx>>13;
      int k = kt*32 + (lane>>4)*8 + j, n = nt*16 + (lane&15);
      float v = (n < DD) ? W[k*DD + n] : Wt[k*DD + (n-DD)];
      Bswz[idx] = f2bf(v);
    } else {
      int t = idx - 32768;
      int which = t >> 14; t &= 16383;
      int j = t & 7, lane = (t>>3)&63, nt = (t>>9)&7, kt = (t>>12)&3;
      int k = kt*32 + (lane>>4)*8 + j, n = nt*16 + (lane&15);
      const float* __restrict__ src = which ? W2 : W1;
      u16* __restrict__ dst = which ? W2swz : W1swz;
      dst[t] = f2bf(src[k*DD + n]);
    }
  }
  if (f < N*32) {
    int r = f >> 5, hl = f & 31;
    float4 xa = *(const float4*)(x    + (size_t)r*DD + hl*4);
    float4 pa = *(const float4*)(perb + (size_t)r*DD + hl*4);
    u32 d0 = (u32)f2bf(xa.x) | ((u32)f2bf(xa.y) << 16);
    u32 d1 = (u32)f2bf(xa.z) | ((u32)f2bf(xa.w) << 16);
    int q0 = (int)rintf(pa.x*PSC); q0 = q0 < -127 ? -127 : (q0 > 127 ? 127 : q0);
    int q1 = (int)rintf(pa.y*PSC); q1 = q1 < -127 ? -127 : (q1 > 127 ? 127 : q1);
    int q2 = (int)rintf(pa.z*PSC); q2 = q2 < -127 ? -127 : (q2 > 127 ? 127 : q2);
    int q3 = (int)rintf(pa.w*PSC); q3 = q3 < -127 ? -127 : (q3 > 127 ? 127 : q3);
    u32 d2 = (u32)(q0 & 0xff) | ((u32)(q1 & 0xff) << 8)
           | ((u32)(q2 & 0xff) << 16) | ((u32)(q3 & 0xff) << 24);
    uint3 o; o.x = d0; o.y = d1; o.z = d2;
    *(uint3*)(Tg + (size_t)r*384 + hl*12) = o;
  }
}

// K2: bucket edges by destination row. Packed 4B/edge: col:u16 | val:f16
// (N<65536; f16 rel err 5e-4 -> negligible).
__global__ __launch_bounds__(256) void k2_bucket(
    const int* __restrict__ row, const int* __restrict__ col,
    const float* __restrict__ val, int E, int* __restrict__ deg,
    u32* __restrict__ perm, int* __restrict__ ovfc, int* __restrict__ ovf)
{
  int e = blockIdx.x*256 + threadIdx.x;
  if (e >= E) return;
  int r = row[e];
  int slot = atomicAdd(&deg[r], 1);
  if (slot < CAP) {
    u32 pk = (u32)(col[e] & 0xffff)
           | ((u32)__half_as_ushort(__float2half(val[e])) << 16);
    perm[(size_t)r*CAP + slot] = pk;
  }
  else { int oi = atomicAdd(ovfc, 1); if (oi < 4096) ovf[oi] = e; }
}

// K3: one wave per row; 384B/edge gathers (12B/lane dwordx3), two wave-halves
// process even/odd edges. Memory-pattern bound: only lever left is bytes/edge
// (R0->R1: halving VMEM instrs at fixed bytes left dur unchanged).
// Lane hl owns elems 4hl..4hl+3 for BOTH x and perb -> aggx2 in-lane.
__global__ __launch_bounds__(256) void k3_spmm(
    const u32* __restrict__ perm, const int* __restrict__ deg,
    const u8* __restrict__ Tg, u16* __restrict__ T2, int N)
{
  int row = blockIdx.x*4 + (threadIdx.x >> 6);
  int l = threadIdx.x & 63;
  if (row >= N) return;
  int dg = deg[row];
  dg = dg < 0 ? 0 : (dg > CAP ? CAP : dg);       // defensive clamp
  const int half = l >> 5, hl = l & 31;
  const int loff = hl * 12;                       // byte offset in 384B row
  float ax[4] = {0.f,0.f,0.f,0.f};
  float ap[4] = {0.f,0.f,0.f,0.f};
  for (int base = 0; base < dg; base += 64) {
    u32 pk = 0;                                   // pad: c=0, v=0 (harmless gather)
    if (base + l < dg) pk = perm[(size_t)row*CAP + base + l];
    int mm = dg - base; if (mm > 64) mm = 64;
    int kmax = (mm + 1) & ~1;                     // round up to even (pad v=0)
    int j = 0;
    for (; j + 8 <= kmax; j += 8) {
      u32 p0 = (u32)__shfl((int)pk, j + half);
      u32 p1 = (u32)__shfl((int)pk, j + 2 + half);
      u32 p2 = (u32)__shfl((int)pk, j + 4 + half);
      u32 p3 = (u32)__shfl((int)pk, j + 6 + half);
      int c0 = p0 & 0xffff; c0 = (c0 < N) ? c0 : 0;
      int c1 = p1 & 0xffff; c1 = (c1 < N) ? c1 : 0;
      int c2 = p2 & 0xffff; c2 = (c2 < N) ? c2 : 0;
      int c3 = p3 & 0xffff; c3 = (c3 < N) ? c3 : 0;
      float v0 = __half2float(__ushort_as_half((u16)(p0 >> 16)));
      float v1 = __half2float(__ushort_as_half((u16)(p1 >> 16)));
      float v2 = __half2float(__ushort_as_half((u16)(p2 >> 16)));
      float v3 = __half2float(__ushort_as_half((u16)(p3 >> 16)));
      uint3 g0 = *(const uint3*)(Tg + (size_t)c0*384 + loff);
      uint3 g1 = *(const uint3*)(Tg + (size_t)c1*384 + loff);
      uint3 g2 = *(const uint3*)(Tg + (size_t)c2*384 + loff);
      uint3 g3 = *(const uint3*)(Tg + (size_t)c3*384 + loff);
      float vq0 = v0*IPSC, vq1 = v1*IPSC, vq2 = v2*IPSC, vq3 = v3*IPSC;
      FMAXP(g0, v0, vq0); FMAXP(g1, v1, vq1);
      FMAXP(g2, v2, vq2); FMAXP(g3, v3, vq3);
    }
    for (; j < kmax; j += 2) {
      u32 p0 = (u32)__shfl((int)pk, j + half);
      int c0 = p0 & 0xffff; c0 = (c0 < N) ? c0 : 0;
      float v0 = __half2float(__ushort_as_half((u16)(p0 >> 16)));
      uint3 g0 = *(const uint3*)(Tg + (size_t)c0*384 + loff);
      float vq0 = v0*IPSC;
      FMAXP(g0, v0, vq0);
    }
  }
  // combine even/odd-edge partials across halves
  #pragma unroll
  for (int i = 0; i < 4; ++i) {
    ax[i] += __shfl_xor(ax[i], 32);
    ap[i] += __shfl_xor(ap[i], 32);
  }
  // T2 row = [aggx1 (128) | aggx2=aggx1+aggp (128)]; half0 writes x1, half1 x2.
  bf16x4 ob;
  #pragma unroll
  for (int i = 0; i < 4; ++i) {
    float o = half ? (ax[i] + ap[i]) : ax[i];
    ob[i] = (short)f2bf(o);
  }
  *(bf16x4*)(T2 + (size_t)row*256 + half*128 + hl*4) = ob;  // 64 lanes x 8B
}

// K3b: overflow fallback (expected empty) — serial RMW on T2 (raw edges).
__global__ __launch_bounds__(256) void k3b_ovf(
    const int* __restrict__ rowI, const int* __restrict__ colI,
    const float* __restrict__ val, const int* __restrict__ ovfc,
    const int* __restrict__ ovf, const u8* __restrict__ Tg,
    u16* __restrict__ T2)
{
  int n = *ovfc; if (n > 4096) n = 4096;
  for (int i = 0; i < n; ++i) {
    int e = ovf[i];
    int r = rowI[e], c = colI[e];
    float v = val[e];
    int d = threadIdx.x;           // 256 threads cover the 256-wide row
    int dl = d & 127;
    const u8* tgc = Tg + (size_t)c*384 + (dl>>2)*12;
    float xv = bf2f(*(const u16*)(tgc + (dl&3)*2));
    float add = v * xv;
    if (d >= 128) {
      int qb = (int)(signed char)tgc[8 + (dl&3)];
      add = v * (xv + (float)qb * IPSC);
    }
    u16* p = &T2[(size_t)r*256 + d];
    *p = f2bf(bf2f(*p) + add);
  }
}

// K4 (fused k4+k5): stage1 split into two N-half passes, half-width C-tile
// (LDS 34.8KB, 4 blocks/CU); shared acc[8] for passA/passB/stage2.
//   passA: [aggx1;aggx2] @ [W|Wt] cols 128-255 -> Ct = [s1|s3] -> AGGb
//   passB: cols 0-127 + bias -> Ct = [s0|s2+b] -> embed (x+perb from Tg); stage2 A
//   stage2: P = Ct @ W1 + b1 -> BN partials + Px/Py
__global__ __launch_bounds__(256, 4) void k4_gemm(
    const u16* __restrict__ T2, const u16* __restrict__ Bswz,
    const u16* __restrict__ W1swz,
    const float* __restrict__ b, const float* __restrict__ bt,
    const float* __restrict__ b1, const u8* __restrict__ Tg,
    u16* __restrict__ AGGb, float* __restrict__ outE,
    u16* __restrict__ Px, u16* __restrict__ Py,
    float* __restrict__ partial, int N, int NB)
{
  __shared__ __align__(16) u16 As1[64*STRA];   // 17408B; later red (f32[1024])
  __shared__ __align__(16) u16 Ct[64*STRA];    // 17408B half C-tile (u16/bf16)
  const int tid = threadIdx.x;
  const int r0 = blockIdx.x * 32;
  // ---- load A (64 rows: 0-31 = aggx1, 32-63 = aggx2) ----
  #pragma unroll
  for (int i = 0; i < 4; ++i) {
    int f = tid + 256*i;            // 1024 chunks: 64 A-rows x 16 chunks of 8
    int row = f >> 4, c8 = f & 15;
    int r = r0 + (row & 31);
    bf16x8 ch = {0,0,0,0,0,0,0,0};
    if (r < N) ch = *(const bf16x8*)(T2 + (size_t)r*256 + (row>>5)*128 + c8*8);
    *(bf16x8*)&As1[row*STRA + c8*8] = ch;
  }
  __syncthreads();                                        // (1)
  const int w = tid >> 6, l = tid & 63;
  const int m = l & 15, q = l >> 4;
  const int arow = w*16 + m;
  f32x4 acc[8];
  // ---- stage1 pass A: global cols 128..255 ([s1|s3]) ----
  #pragma unroll
  for (int nt = 0; nt < 8; ++nt) acc[nt] = (f32x4){0.f,0.f,0.f,0.f};
  #pragma unroll
  for (int kt = 0; kt < 4; ++kt) {
    bf16x8 af = *(const bf16x8*)&As1[arow*STRA + kt*32 + q*8];
    #pragma unroll
    for (int nt = 0; nt < 8; ++nt) {
      bf16x8 bfr = *(const bf16x8*)(Bswz + ((size_t)(kt*16 + 8 + nt)*64 + l)*8);
      acc[nt] = __builtin_amdgcn_mfma_f32_16x16x32_bf16(af, bfr, acc[nt], 0, 0, 0);
    }
  }
  #pragma unroll
  for (int nt = 0; nt < 8; ++nt) {
    float bv = bt[nt*16 + m];                             // col = 128+nt*16+m
    #pragma unroll
    for (int i = 0; i < 4; ++i)
      Ct[(w*16 + q*4 + i)*STRA + nt*16 + m] = f2bf(acc[nt][i] + bv);
  }
  __syncthreads();                                        // (2)
  // ---- AGGb write: [s1|s3] (rows<32 -> s1 @0, rows>=32 -> s3 @128) ----
  {
    const int ar = tid >> 2, p = tid & 3;
    const int src = r0 + (ar & 31);
    if (src < N) {
      u16* dp = AGGb + (size_t)src*256 + (ar>>5)*128 + p*32;
      const u16* sp = &Ct[ar*STRA + p*32];
      #pragma unroll
      for (int i = 0; i < 4; ++i)
        *(bf16x8*)(dp + i*8) = *(const bf16x8*)(sp + i*8);
    }
  }
  __syncthreads();                                        // (3) Ct reads done
  // ---- stage1 pass B: global cols 0..127 ([s0|s2] + bias) ----
  #pragma unroll
  for (int nt = 0; nt < 8; ++nt) acc[nt] = (f32x4){0.f,0.f,0.f,0.f};
  #pragma unroll
  for (int kt = 0; kt < 4; ++kt) {
    bf16x8 af = *(const bf16x8*)&As1[arow*STRA + kt*32 + q*8];
    #pragma unroll
    for (int nt = 0; nt < 8; ++nt) {
      bf16x8 bfr = *(const bf16x8*)(Bswz + ((size_t)(kt*16 + nt)*64 + l)*8);
      acc[nt] = __builtin_amdgcn_mfma_f32_16x16x32_bf16(af, bfr, acc[nt], 0, 0, 0);
    }
  }
  #pragma unroll
  for (int nt = 0; nt < 8; ++nt) {
    float bv = b[nt*16 + m];
    #pragma unroll
    for (int i = 0; i < 4; ++i)
      Ct[(w*16 + q*4 + i)*STRA + nt*16 + m] = f2bf(acc[nt][i] + bv);
  }
  __syncthreads();                                        // (4)
  // ---- embed = x + perb + s2 (Ct rows 32-63, bias incl.); x,perb from Tg ----
  #pragma unroll
  for (int i = 0; i < 2; ++i) {
    int f = tid + 256*i;            // 512 chunks: 32 rows x 16 chunks of 8
    int rr = f >> 4, c8 = f & 15;
    int src = r0 + rr;
    if (src < N) {
      const u16* cp = &Ct[(32+rr)*STRA + c8*8];
      const u8* tg = Tg + (size_t)src*384 + c8*24;   // two 12B chunks
      uint3 ga = *(const uint3*)tg;
      uint3 gb = *(const uint3*)(tg + 12);
      int da = (int)ga.z, db = (int)gb.z;
      float4 e0, e1;
      e0.x = bflo(ga.x) + IPSC*(float)(signed char)(da)     + bf2f(cp[0]);
      e0.y = bfhi(ga.x) + IPSC*(float)(signed char)(da>>8)  + bf2f(cp[1]);
      e0.z = bflo(ga.y) + IPSC*(float)(signed char)(da>>16) + bf2f(cp[2]);
      e0.w = bfhi(ga.y) + IPSC*(float)(da>>24)              + bf2f(cp[3]);
      e1.x = bflo(gb.x) + IPSC*(float)(signed char)(db)     + bf2f(cp[4]);
      e1.y = bfhi(gb.x) + IPSC*(float)(signed char)(db>>8)  + bf2f(cp[5]);
      e1.z = bflo(gb.y) + IPSC*(float)(signed char)(db>>16) + bf2f(cp[6]);
      e1.w = bfhi(gb.y) + IPSC*(float)(db>>24)              + bf2f(cp[7]);
      float* er = outE + (size_t)src*DD + c8*8;
      *(float4*)er = e0;
      *(float4*)(er+4) = e1;
    }
  }
  // ---- stage2 MFMA: P = Ct[:, 0:128] @ W1 (A read in-place, stride STRA) ----
  #pragma unroll
  for (int nt = 0; nt < 8; ++nt) acc[nt] = (f32x4){0.f,0.f,0.f,0.f};
  #pragma unroll
  for (int kt = 0; kt < 4; ++kt) {
    bf16x8 af = *(const bf16x8*)&Ct[arow*STRA + kt*32 + q*8];
    #pragma unroll
    for (int nt = 0; nt < 8; ++nt) {
      bf16x8 bfr = *(const bf16x8*)(W1swz + ((size_t)(kt*8+nt)*64 + l)*8);
      acc[nt] = __builtin_amdgcn_mfma_f32_16x16x32_bf16(af, bfr, acc[nt], 0, 0, 0);
    }
  }
  // ---- b1 + validity + BN partial sums (red lives in As1 region; As1 dead) ----
  float* red = (float*)As1;         // [type(2)][wave(4)*128 + col] = 4KB
  #pragma unroll
  for (int nt = 0; nt < 8; ++nt) {
    float bv = b1[nt*16 + m];
    float sum = 0.f, sq = 0.f;
    #pragma unroll
    for (int i = 0; i < 4; ++i) {
      int src = r0 + ((w*16 + q*4 + i) & 31);
      if (src < N) acc[nt][i] += bv; else acc[nt][i] = 0.f;
      sum += acc[nt][i]; sq += acc[nt][i]*acc[nt][i];
    }
    sum += __shfl_xor(sum, 16); sum += __shfl_xor(sum, 32);
    sq  += __shfl_xor(sq, 16);  sq  += __shfl_xor(sq, 32);
    if (l < 16) {
      red[      w*128 + nt*16 + l] = sum;
      red[512 + w*128 + nt*16 + l] = sq;
    }
  }
  __syncthreads();                                        // (5)
  {
    // waves 0,1 = rows 0-31 = seg0 (Px); waves 2,3 = rows 32-63 = seg1 (Py)
    int type = tid >> 7, col = tid & 127;
    float v0 = red[type*512 +   0 + col] + red[type*512 + 128 + col];
    float v1 = red[type*512 + 256 + col] + red[type*512 + 384 + col];
    partial[((size_t)0*NB + blockIdx.x)*256 + tid] = v0;
    partial[((size_t)1*NB + blockIdx.x)*256 + tid] = v1;
  }
  // ---- P-tile (bf16) into Ct: all Ct reads completed before sync(5) ----
  #pragma unroll
  for (int nt = 0; nt < 8; ++nt)
    #pragma unroll
    for (int i = 0; i < 4; ++i)
      Ct[(w*16 + q*4 + i)*STRA + nt*16 + m] = f2bf(acc[nt][i]);
  __syncthreads();                                        // (6)
  // ---- P write: rows 0-31 -> Px, rows 32-63 -> Py ----
  {
    const int ar = tid >> 2, p = tid & 3;
    const int src = r0 + (ar & 31);
    if (src < N) {
      const u16* sp = &Ct[ar*STRA + p*32];
      u16* dp = ((ar >> 5) ? Py : Px) + (size_t)src*DD + p*32;
      #pragma unroll
      for (int i = 0; i < 4; ++i)
        *(bf16x8*)(dp + i*8) = *(const bf16x8*)(sp + i*8);
    }
  }
}

// K5b: reduce per-block partials into stats (few atomics).
__global__ __launch_bounds__(256) void k5b_stats(
    const float* __restrict__ partial, float* __restrict__ stats, int nb)
{
  int seg = blockIdx.y, chunk = blockIdx.x, t = threadIdx.x;
  int per = (nb + gridDim.x - 1) / gridDim.x;
  int lo = chunk*per, hi = lo+per; if (hi > nb) hi = nb;
  float s = 0.f;
  const float* p = partial + (size_t)seg*nb*256;
  for (int i = lo; i < hi; ++i) s += p[(size_t)i*256 + t];
  atomicAdd(&stats[seg*256 + t], s);
}

// K6: BN+PReLU (bf16 P) -> MFMA GEMM2 (+b2) -> parallel per-row BYOL cosine ->
// 1 atomic/block. NO device fence (R1 lesson). AGGb [s1|s3] 256 u16/row:
// seg0 target = s3 (off 128), seg1 target = s1 (off 0).
__global__ __launch_bounds__(256) void k6_gemm_loss(
    const u16* __restrict__ Px, const u16* __restrict__ Py,
    const u16* __restrict__ AGGb, const float* __restrict__ stats,
    const float* __restrict__ gamma, const float* __restrict__ beta,
    const float* __restrict__ aP, const u16* __restrict__ W2swz,
    const float* __restrict__ b2, float* __restrict__ gloss, int N)
{
  __shared__ __align__(16) float Cs[64*STRCF];   // 33792B; aliased as As (17408B)
  u16* As = (u16*)Cs;
  __shared__ float s1s[128], s2s[128];
  __shared__ float gred[4];
  const int tid = threadIdx.x;
  const int seg = blockIdx.y;
  const u16* __restrict__ P = seg ? Py : Px;
  const int toff = seg ? 0 : 128;
  const float invN = 1.f / (float)N;
  if (tid < 128) {
    float mu = stats[seg*256 + tid] * invN;
    float var = stats[seg*256 + 128 + tid] * invN - mu*mu;
    float rstd = rsqrtf(var + 1e-5f);
    float s1 = rstd * gamma[tid];
    s1s[tid] = s1;
    s2s[tid] = beta[tid] - mu*s1;
  }
  const float alpha = aP[0];
  const int r0 = blockIdx.x * 64;
  __syncthreads();
  #pragma unroll
  for (int i = 0; i < 4; ++i) {
    int f = tid + 256*i;
    int row = f >> 4, c8 = f & 15;
    int r = r0 + row;
    bf16x8 ch = {0,0,0,0,0,0,0,0};
    if (r < N) ch = *(const bf16x8*)(P + (size_t)r*DD + c8*8);
    bf16x8 a;
    #pragma unroll
    for (int t2 = 0; t2 < 8; ++t2) {
      int colc = c8*8 + t2;
      float hv = bf2f((u16)ch[t2]);
      float hn = hv*s1s[colc] + s2s[colc];
      hn = hn >= 0.f ? hn : alpha*hn;
      a[t2] = (short)f2bf(hn);
    }
    *(bf16x8*)&As[row*STRA + c8*8] = a;
  }
  __syncthreads();
  const int w = tid >> 6, l = tid & 63;
  const int m = l & 15, q = l >> 4;
  f32x4 acc[8];
  #pragma unroll
  for (int nt = 0; nt < 8; ++nt) acc[nt] = (f32x4){0.f,0.f,0.f,0.f};
  const int arow = w*16 + m;
  #pragma unroll
  for (int kt = 0; kt < 4; ++kt) {
    bf16x8 af = *(const bf16x8*)&As[arow*STRA + kt*32 + q*8];
    #pragma unroll
    for (int nt = 0; nt < 8; ++nt) {
      bf16x8 bfr = *(const bf16x8*)(W2swz + ((size_t)(kt*8+nt)*64 + l)*8);
      acc[nt] = __builtin_amdgcn_mfma_f32_16x16x32_bf16(af, bfr, acc[nt], 0, 0, 0);
    }
  }
  __syncthreads();                  // As dead; Cs writes follow (aliased)
  #pragma unroll
  for (int nt = 0; nt < 8; ++nt) {
    float bv = b2[nt*16 + m];
    #pragma unroll
    for (int i = 0; i < 4; ++i)
      Cs[(w*16 + q*4 + i)*STRCF + nt*16 + m] = acc[nt][i] + bv;
  }
  __syncthreads();
  // Parallel BYOL cosine: 4 lanes per row; xor1+xor2 completes row sums;
  // xor4..32 sums 16 distinct rows once per qq-group (no /4 — R2 lesson).
  {
    const int rt = tid >> 2, qq = tid & 3;
    const int r = r0 + rt;
    float pp = 0.f, tt = 0.f, pt = 0.f;
    if (r < N) {
      const float* prow = &Cs[rt*STRCF + qq*32];
      const u16* trow = AGGb + (size_t)r*256 + toff + qq*32;
      #pragma unroll
      for (int i = 0; i < 4; ++i) {
        float4 pa = *(const float4*)(prow + i*8);
        float4 pb = *(const float4*)(prow + i*8 + 4);
        uint4 twv = *(const uint4*)(trow + i*8);
        float t0=bflo(twv.x), t1=bfhi(twv.x), t2=bflo(twv.y), t3=bfhi(twv.y);
        float t4=bflo(twv.z), t5=bfhi(twv.z), t6=bflo(twv.w), t7=bfhi(twv.w);
        pp += pa.x*pa.x + pa.y*pa.y + pa.z*pa.z + pa.w*pa.w
            + pb.x*pb.x + pb.y*pb.y + pb.z*pb.z + pb.w*pb.w;
        tt += t0*t0 + t1*t1 + t2*t2 + t3*t3 + t4*t4 + t5*t5 + t6*t6 + t7*t7;
        pt += pa.x*t0 + pa.y*t1 + pa.z*t2 + pa.w*t3
            + pb.x*t4 + pb.y*t5 + pb.z*t6 + pb.w*t7;
      }
    }
    pp += __shfl_xor(pp, 1); pp += __shfl_xor(pp, 2);
    tt += __shfl_xor(tt, 1); tt += __shfl_xor(tt, 2);
    pt += __shfl_xor(pt, 1); pt += __shfl_xor(pt, 2);
    float lsum = (r < N) ? (2.f - 2.f * pt * rsqrtf(pp * tt)) : 0.f;
    lsum += __shfl_xor(lsum, 4);  lsum += __shfl_xor(lsum, 8);
    lsum += __shfl_xor(lsum, 16); lsum += __shfl_xor(lsum, 32);
    if (l == 0) gred[w] = lsum;
  }
  __syncthreads();
  if (tid == 0) atomicAdd(gloss, gred[0]+gred[1]+gred[2]+gred[3]);
}

__global__ void k7_loss(const float* __restrict__ gloss, float* __restrict__ out, int N, int total)
{
  out[total] = gloss[0] / (float)N;
}

extern "C" void kernel_launch(void* const* d_in, const int* in_sizes, int n_in,
                              void* d_out, int out_size, void* d_ws, size_t ws_size,
                              hipStream_t stream)
{
  const float* x    = (const float*)d_in[0];
  const float* perb = (const float*)d_in[1];
  const int*   erow = (const int*)d_in[2];
  const int*   ecol = (const int*)d_in[3];
  const float* eval_= (const float*)d_in[4];
  const float* W    = (const float*)d_in[5];
  const float* b    = (const float*)d_in[6];
  const float* Wt   = (const float*)d_in[7];
  const float* bt   = (const float*)d_in[8];
  const float* W1   = (const float*)d_in[9];
  const float* b1   = (const float*)d_in[10];
  const float* gam  = (const float*)d_in[11];
  const float* bet  = (const float*)d_in[12];
  const float* aP   = (const float*)d_in[13];
  const float* W2   = (const float*)d_in[14];
  const float* b2   = (const float*)d_in[15];
  const int N = in_sizes[0] / DD;
  const int E = in_sizes[2];
  const int NB4 = (N + 31)/32;
  const int NB5 = (N + 63)/64;

  char* ws = (char*)d_ws;
  size_t off = 0;
  auto alloc = [&](size_t bytes) -> void* {
    void* p = ws + off;
    off += (bytes + 255) & ~(size_t)255;
    return p;
  };
  u16*   AGGb = (u16*)  alloc((size_t)N*256*sizeof(u16));   // 25.6 MB [s1|s3]
  u8*    Tg   = (u8*)   alloc((size_t)N*384);               // 19.2 MB gather table
  u16*   T2   = (u16*)  alloc((size_t)N*256*sizeof(u16));   // 25.6 MB
  u16*   Px   = (u16*)  alloc((size_t)N*DD*sizeof(u16));    // 12.8 MB
  u16*   Py   = (u16*)  alloc((size_t)N*DD*sizeof(u16));    // 12.8 MB
  int*   deg  = (int*)  alloc((size_t)N*sizeof(int));
  float* stats= (float*)alloc(512*sizeof(float));
  float* gloss= (float*)alloc(256);
  int*   ovfc = (int*)((char*)gloss + 64);
  u32*   perm = (u32*)  alloc((size_t)N*CAP*sizeof(u32));   // 12.8 MB packed
  int*   ovf  = (int*)  alloc(4096*sizeof(int));
  u16*   Bswz = (u16*)  alloc(32768*sizeof(u16));
  u16*   W1swz= (u16*)  alloc(16384*sizeof(u16));
  u16*   W2swz= (u16*)  alloc(16384*sizeof(u16));
  float* partial = (float*)alloc((size_t)2*NB4*256*sizeof(float)); // 3.2 MB
  if (ws_size < off) return;

  kU_init<<<(N*32 + 255)/256, 256, 0, stream>>>(x, perb, W, Wt, W1, W2,
                                                Tg, Bswz, W1swz, W2swz,
                                                deg, stats, gloss, N);
  k2_bucket<<<(E + 255)/256, 256, 0, stream>>>(erow, ecol, eval_, E, deg, perm, ovfc, ovf);
  k3_spmm<<<(N + 3)/4, 256, 0, stream>>>(perm, deg, Tg, T2, N);
  k3b_ovf<<<1, 256, 0, stream>>>(erow, ecol, eval_, ovfc, ovf, Tg, T2);
  k4_gemm<<<NB4, 256, 0, stream>>>(T2, Bswz, W1swz, b, bt, b1, Tg,
                                   AGGb, (float*)d_out, Px, Py, partial, N, NB4);
  k5b_stats<<<dim3(16, 2), 256, 0, stream>>>(partial, stats, NB4);
  k6_gemm_loss<<<dim3(NB5, 2), 256, 0, stream>>>(Px, Py, AGGb, stats, gam, bet, aP,
                                                 W2swz, b2, gloss, N);
  k7_loss<<<1, 1, 0, stream>>>(gloss, (float*)d_out, N, N*DD);
}

// Round 7
// 299.756 us; speedup vs baseline: 1.1091x; 1.0469x over previous
//
#include <hip/hip_runtime.h>
#include <hip/hip_fp16.h>
#include <stdint.h>

typedef unsigned short u16;
typedef unsigned int u32;
typedef unsigned char u8;
typedef __attribute__((ext_vector_type(8))) short bf16x8;
typedef __attribute__((ext_vector_type(4))) short bf16x4;
typedef __attribute__((ext_vector_type(4))) float f32x4;

#define DD 128
#define CAP 64     // Poisson(16): P(deg>64) ~ 1e-20; overflow path still correct
#define STRA 136   // A/C half-tile LDS stride (u16): 272B rows, 16B-aligned
#define STRCF 132  // k6 f32 C-tile stride
#define PSC 256.f  // perb int8 scale: q = rint(perb*256), |err| <= 0.002
#define IPSC (1.f/256.f)

__device__ __forceinline__ float bflo(u32 u){ return __uint_as_float(u<<16); }
__device__ __forceinline__ float bfhi(u32 u){ return __uint_as_float(u & 0xffff0000u); }
__device__ __forceinline__ float bf2f(u16 u){ return __uint_as_float(((u32)u)<<16); }
__device__ __forceinline__ u16 f2bf(float f){
  u32 u = __float_as_uint(f);
  return (u16)((u + 0x7fffu + ((u>>16)&1u)) >> 16);   // RNE
}

// Tg row (384B): 32 chunks of 12B; chunk hl = [4x bf16 x (8B) | 4x int8 perb (4B)]
#define FMAXP(g, vv, vqv) do { \
    ax[0] += (vv)*bflo((g).x); ax[1] += (vv)*bfhi((g).x); \
    ax[2] += (vv)*bflo((g).y); ax[3] += (vv)*bfhi((g).y); \
    int d_ = (int)(g).z; \
    ap[0] += (vqv)*(float)(signed char)(d_); \
    ap[1] += (vqv)*(float)(signed char)(d_>>8); \
    ap[2] += (vqv)*(float)(signed char)(d_>>16); \
    ap[3] += (vqv)*(float)(d_>>24); } while(0)

// kU: fused init. (a) zero control region (COMPUTE kernel, never SDMA/memset —
// graph replay ordering), (b) pre-swizzle weights into MFMA B-fragment order,
// (c) build gather table Tg (bf16 x + int8 perb, 384B/row).
__global__ __launch_bounds__(256) void kU_init(
    const float* __restrict__ x, const float* __restrict__ perb,
    const float* __restrict__ W, const float* __restrict__ Wt,
    const float* __restrict__ W1, const float* __restrict__ W2,
    u8* __restrict__ Tg, u16* __restrict__ Bswz,
    u16* __restrict__ W1swz, u16* __restrict__ W2swz,
    int* __restrict__ deg, float* __restrict__ stats,
    float* __restrict__ gbuf, int N)
{
  int f = blockIdx.x*256 + threadIdx.x;
  if (f < N) deg[f] = 0;
  if (f < 512) stats[f] = 0.f;
  if (f < 64) gbuf[f] = 0.f;   // covers gloss + ovfc (256B block)
  if (f < 65536) {
    int idx = f;
    if (idx < 32768) {
      int j = idx & 7, lane = (idx>>3)&63, nt = (idx>>9)&15, kt = idx>>13;
      int k = kt*32 + (lane>>4)*8 + j, n = nt*16 + (lane&15);
      float v = (n < DD) ? W[k*DD + n] : Wt[k*DD + (n-DD)];
      Bswz[idx] = f2bf(v);
    } else {
      int t = idx - 32768;
      int which = t >> 14; t &= 16383;
      int j = t & 7, lane = (t>>3)&63, nt = (t>>9)&7, kt = (t>>12)&3;
      int k = kt*32 + (lane>>4)*8 + j, n = nt*16 + (lane&15);
      const float* __restrict__ src = which ? W2 : W1;
      u16* __restrict__ dst = which ? W2swz : W1swz;
      dst[t] = f2bf(src[k*DD + n]);
    }
  }
  if (f < N*32) {
    int r = f >> 5, hl = f & 31;
    float4 xa = *(const float4*)(x    + (size_t)r*DD + hl*4);
    float4 pa = *(const float4*)(perb + (size_t)r*DD + hl*4);
    u32 d0 = (u32)f2bf(xa.x) | ((u32)f2bf(xa.y) << 16);
    u32 d1 = (u32)f2bf(xa.z) | ((u32)f2bf(xa.w) << 16);
    int q0 = (int)rintf(pa.x*PSC); q0 = q0 < -127 ? -127 : (q0 > 127 ? 127 : q0);
    int q1 = (int)rintf(pa.y*PSC); q1 = q1 < -127 ? -127 : (q1 > 127 ? 127 : q1);
    int q2 = (int)rintf(pa.z*PSC); q2 = q2 < -127 ? -127 : (q2 > 127 ? 127 : q2);
    int q3 = (int)rintf(pa.w*PSC); q3 = q3 < -127 ? -127 : (q3 > 127 ? 127 : q3);
    u32 d2 = (u32)(q0 & 0xff) | ((u32)(q1 & 0xff) << 8)
           | ((u32)(q2 & 0xff) << 16) | ((u32)(q3 & 0xff) << 24);
    uint3 o; o.x = d0; o.y = d1; o.z = d2;
    *(uint3*)(Tg + (size_t)r*384 + hl*12) = o;
  }
}

// K2: bucket edges by destination row. Packed 4B/edge: col:u16 | val:f16.
__global__ __launch_bounds__(256) void k2_bucket(
    const int* __restrict__ row, const int* __restrict__ col,
    const float* __restrict__ val, int E, int* __restrict__ deg,
    u32* __restrict__ perm, int* __restrict__ ovfc, int* __restrict__ ovf)
{
  int e = blockIdx.x*256 + threadIdx.x;
  if (e >= E) return;
  int r = row[e];
  int slot = atomicAdd(&deg[r], 1);
  if (slot < CAP) {
    u32 pk = (u32)(col[e] & 0xffff)
           | ((u32)__half_as_ushort(__float2half(val[e])) << 16);
    perm[(size_t)r*CAP + slot] = pk;
  }
  else { int oi = atomicAdd(ovfc, 1); if (oi < 4096) ovf[oi] = e; }
}

// K3: one wave per row; 384B/edge gathers (12B/lane dwordx3), two wave-halves
// process even/odd edges. Random-gather memory-pattern bound.
__global__ __launch_bounds__(256) void k3_spmm(
    const u32* __restrict__ perm, const int* __restrict__ deg,
    const u8* __restrict__ Tg, u16* __restrict__ T2, int N)
{
  int row = blockIdx.x*4 + (threadIdx.x >> 6);
  int l = threadIdx.x & 63;
  if (row >= N) return;
  int dg = deg[row];
  dg = dg < 0 ? 0 : (dg > CAP ? CAP : dg);       // defensive clamp
  const int half = l >> 5, hl = l & 31;
  const int loff = hl * 12;                       // byte offset in 384B row
  float ax[4] = {0.f,0.f,0.f,0.f};
  float ap[4] = {0.f,0.f,0.f,0.f};
  for (int base = 0; base < dg; base += 64) {
    u32 pk = 0;                                   // pad: c=0, v=0 (harmless gather)
    if (base + l < dg) pk = perm[(size_t)row*CAP + base + l];
    int mm = dg - base; if (mm > 64) mm = 64;
    int kmax = (mm + 1) & ~1;                     // round up to even (pad v=0)
    int j = 0;
    for (; j + 8 <= kmax; j += 8) {
      u32 p0 = (u32)__shfl((int)pk, j + half);
      u32 p1 = (u32)__shfl((int)pk, j + 2 + half);
      u32 p2 = (u32)__shfl((int)pk, j + 4 + half);
      u32 p3 = (u32)__shfl((int)pk, j + 6 + half);
      int c0 = p0 & 0xffff; c0 = (c0 < N) ? c0 : 0;
      int c1 = p1 & 0xffff; c1 = (c1 < N) ? c1 : 0;
      int c2 = p2 & 0xffff; c2 = (c2 < N) ? c2 : 0;
      int c3 = p3 & 0xffff; c3 = (c3 < N) ? c3 : 0;
      float v0 = __half2float(__ushort_as_half((u16)(p0 >> 16)));
      float v1 = __half2float(__ushort_as_half((u16)(p1 >> 16)));
      float v2 = __half2float(__ushort_as_half((u16)(p2 >> 16)));
      float v3 = __half2float(__ushort_as_half((u16)(p3 >> 16)));
      uint3 g0 = *(const uint3*)(Tg + (size_t)c0*384 + loff);
      uint3 g1 = *(const uint3*)(Tg + (size_t)c1*384 + loff);
      uint3 g2 = *(const uint3*)(Tg + (size_t)c2*384 + loff);
      uint3 g3 = *(const uint3*)(Tg + (size_t)c3*384 + loff);
      float vq0 = v0*IPSC, vq1 = v1*IPSC, vq2 = v2*IPSC, vq3 = v3*IPSC;
      FMAXP(g0, v0, vq0); FMAXP(g1, v1, vq1);
      FMAXP(g2, v2, vq2); FMAXP(g3, v3, vq3);
    }
    for (; j < kmax; j += 2) {
      u32 p0 = (u32)__shfl((int)pk, j + half);
      int c0 = p0 & 0xffff; c0 = (c0 < N) ? c0 : 0;
      float v0 = __half2float(__ushort_as_half((u16)(p0 >> 16)));
      uint3 g0 = *(const uint3*)(Tg + (size_t)c0*384 + loff);
      float vq0 = v0*IPSC;
      FMAXP(g0, v0, vq0);
    }
  }
  // combine even/odd-edge partials across halves
  #pragma unroll
  for (int i = 0; i < 4; ++i) {
    ax[i] += __shfl_xor(ax[i], 32);
    ap[i] += __shfl_xor(ap[i], 32);
  }
  // T2 row = [aggx1 (128) | aggx2=aggx1+aggp (128)]; half0 writes x1, half1 x2.
  bf16x4 ob;
  #pragma unroll
  for (int i = 0; i < 4; ++i) {
    float o = half ? (ax[i] + ap[i]) : ax[i];
    ob[i] = (short)f2bf(o);
  }
  *(bf16x4*)(T2 + (size_t)row*256 + half*128 + hl*4) = ob;  // 64 lanes x 8B
}

// K3b: overflow fallback (expected empty) — serial RMW on T2 (raw edges).
__global__ __launch_bounds__(256) void k3b_ovf(
    const int* __restrict__ rowI, const int* __restrict__ colI,
    const float* __restrict__ val, const int* __restrict__ ovfc,
    const int* __restrict__ ovf, const u8* __restrict__ Tg,
    u16* __restrict__ T2)
{
  int n = *ovfc; if (n > 4096) n = 4096;
  for (int i = 0; i < n; ++i) {
    int e = ovf[i];
    int r = rowI[e], c = colI[e];
    float v = val[e];
    int d = threadIdx.x;           // 256 threads cover the 256-wide row
    int dl = d & 127;
    const u8* tgc = Tg + (size_t)c*384 + (dl>>2)*12;
    float xv = bf2f(*(const u16*)(tgc + (dl&3)*2));
    float add = v * xv;
    if (d >= 128) {
      int qb = (int)(signed char)tgc[8 + (dl&3)];
      add = v * (xv + (float)qb * IPSC);
    }
    u16* p = &T2[(size_t)r*256 + d];
    *p = f2bf(bf2f(*p) + add);
  }
}

// K4 (fused k4+k5, R7 wave-per-column-slice): wave w owns cols w*32..w*32+31
// over ALL 64 rows (rt=0..3 row-tiles, ntl=0..1). Per pass only 8 B-fragments
// per wave, HOISTED into registers before the MFMA loop (was 32 L2-latency
// loads interleaved with MFMA x3 passes = the R6 latency wall).
//   passA: cols 128-255 -> Ct=[s1|s3] -> AGGb
//   passB: cols 0-127 + bias -> Ct=[s0|s2+b] -> embed; stage2 A-operand
//   stage2: P = Ct @ W1 + b1 -> BN partials (per-wave disjoint cols) + Px/Py
// Numerics bit-identical to R6.
__global__ __launch_bounds__(256, 4) void k4_gemm(
    const u16* __restrict__ T2, const u16* __restrict__ Bswz,
    const u16* __restrict__ W1swz,
    const float* __restrict__ b, const float* __restrict__ bt,
    const float* __restrict__ b1, const u8* __restrict__ Tg,
    u16* __restrict__ AGGb, float* __restrict__ outE,
    u16* __restrict__ Px, u16* __restrict__ Py,
    float* __restrict__ partial, int N, int NB)
{
  __shared__ __align__(16) u16 As1[64*STRA];   // 17408B; later red (f32[512])
  __shared__ __align__(16) u16 Ct[64*STRA];    // 17408B half C-tile (u16/bf16)
  const int tid = threadIdx.x;
  const int r0 = blockIdx.x * 32;
  // ---- load A (64 rows: 0-31 = aggx1, 32-63 = aggx2) ----
  #pragma unroll
  for (int i = 0; i < 4; ++i) {
    int f = tid + 256*i;            // 1024 chunks: 64 A-rows x 16 chunks of 8
    int row = f >> 4, c8 = f & 15;
    int r = r0 + (row & 31);
    bf16x8 ch = {0,0,0,0,0,0,0,0};
    if (r < N) ch = *(const bf16x8*)(T2 + (size_t)r*256 + (row>>5)*128 + c8*8);
    *(bf16x8*)&As1[row*STRA + c8*8] = ch;
  }
  __syncthreads();                                        // (1)
  const int w = tid >> 6, l = tid & 63;
  const int m = l & 15, q = l >> 4;
  const int cbase = w*32 + m;        // this wave's column base (+ntl*16)
  f32x4 acc[4][2];
  bf16x8 bfrag[2][4];
  // ---- stage1 pass A: global cols 128..255 ([s1|s3]) ----
  #pragma unroll
  for (int ntl = 0; ntl < 2; ++ntl)
    #pragma unroll
    for (int kt = 0; kt < 4; ++kt)
      bfrag[ntl][kt] = *(const bf16x8*)(Bswz + ((size_t)(kt*16 + 8 + w*2 + ntl)*64 + l)*8);
  #pragma unroll
  for (int rt = 0; rt < 4; ++rt) {
    acc[rt][0] = (f32x4){0.f,0.f,0.f,0.f};
    acc[rt][1] = (f32x4){0.f,0.f,0.f,0.f};
  }
  #pragma unroll
  for (int kt = 0; kt < 4; ++kt)
    #pragma unroll
    for (int rt = 0; rt < 4; ++rt) {
      bf16x8 af = *(const bf16x8*)&As1[(rt*16 + m)*STRA + kt*32 + q*8];
      acc[rt][0] = __builtin_amdgcn_mfma_f32_16x16x32_bf16(af, bfrag[0][kt], acc[rt][0], 0, 0, 0);
      acc[rt][1] = __builtin_amdgcn_mfma_f32_16x16x32_bf16(af, bfrag[1][kt], acc[rt][1], 0, 0, 0);
    }
  #pragma unroll
  for (int ntl = 0; ntl < 2; ++ntl) {
    float bv = bt[cbase + ntl*16];
    #pragma unroll
    for (int rt = 0; rt < 4; ++rt)
      #pragma unroll
      for (int i = 0; i < 4; ++i)
        Ct[(rt*16 + q*4 + i)*STRA + cbase + ntl*16] = f2bf(acc[rt][ntl][i] + bv);
  }
  __syncthreads();                                        // (2)
  // ---- AGGb write: [s1|s3] (rows<32 -> s1 @0, rows>=32 -> s3 @128) ----
  {
    const int ar = tid >> 2, p = tid & 3;
    const int src = r0 + (ar & 31);
    if (src < N) {
      u16* dp = AGGb + (size_t)src*256 + (ar>>5)*128 + p*32;
      const u16* sp = &Ct[ar*STRA + p*32];
      #pragma unroll
      for (int i = 0; i < 4; ++i)
        *(bf16x8*)(dp + i*8) = *(const bf16x8*)(sp + i*8);
    }
  }
  __syncthreads();                                        // (3) Ct reads done
  // ---- stage1 pass B: global cols 0..127 ([s0|s2] + bias) ----
  #pragma unroll
  for (int ntl = 0; ntl < 2; ++ntl)
    #pragma unroll
    for (int kt = 0; kt < 4; ++kt)
      bfrag[ntl][kt] = *(const bf16x8*)(Bswz + ((size_t)(kt*16 + w*2 + ntl)*64 + l)*8);
  #pragma unroll
  for (int rt = 0; rt < 4; ++rt) {
    acc[rt][0] = (f32x4){0.f,0.f,0.f,0.f};
    acc[rt][1] = (f32x4){0.f,0.f,0.f,0.f};
  }
  #pragma unroll
  for (int kt = 0; kt < 4; ++kt)
    #pragma unroll
    for (int rt = 0; rt < 4; ++rt) {
      bf16x8 af = *(const bf16x8*)&As1[(rt*16 + m)*STRA + kt*32 + q*8];
      acc[rt][0] = __builtin_amdgcn_mfma_f32_16x16x32_bf16(af, bfrag[0][kt], acc[rt][0], 0, 0, 0);
      acc[rt][1] = __builtin_amdgcn_mfma_f32_16x16x32_bf16(af, bfrag[1][kt], acc[rt][1], 0, 0, 0);
    }
  #pragma unroll
  for (int ntl = 0; ntl < 2; ++ntl) {
    float bv = b[cbase + ntl*16];
    #pragma unroll
    for (int rt = 0; rt < 4; ++rt)
      #pragma unroll
      for (int i = 0; i < 4; ++i)
        Ct[(rt*16 + q*4 + i)*STRA + cbase + ntl*16] = f2bf(acc[rt][ntl][i] + bv);
  }
  __syncthreads();                                        // (4)
  // ---- embed = x + perb + s2 (Ct rows 32-63, bias incl.); x,perb from Tg ----
  #pragma unroll
  for (int i = 0; i < 2; ++i) {
    int f = tid + 256*i;            // 512 chunks: 32 rows x 16 chunks of 8
    int rr = f >> 4, c8 = f & 15;
    int src = r0 + rr;
    if (src < N) {
      const u16* cp = &Ct[(32+rr)*STRA + c8*8];
      const u8* tg = Tg + (size_t)src*384 + c8*24;   // two 12B chunks
      uint3 ga = *(const uint3*)tg;
      uint3 gb = *(const uint3*)(tg + 12);
      int da = (int)ga.z, db = (int)gb.z;
      float4 e0, e1;
      e0.x = bflo(ga.x) + IPSC*(float)(signed char)(da)     + bf2f(cp[0]);
      e0.y = bfhi(ga.x) + IPSC*(float)(signed char)(da>>8)  + bf2f(cp[1]);
      e0.z = bflo(ga.y) + IPSC*(float)(signed char)(da>>16) + bf2f(cp[2]);
      e0.w = bfhi(ga.y) + IPSC*(float)(da>>24)              + bf2f(cp[3]);
      e1.x = bflo(gb.x) + IPSC*(float)(signed char)(db)     + bf2f(cp[4]);
      e1.y = bfhi(gb.x) + IPSC*(float)(signed char)(db>>8)  + bf2f(cp[5]);
      e1.z = bflo(gb.y) + IPSC*(float)(signed char)(db>>16) + bf2f(cp[6]);
      e1.w = bfhi(gb.y) + IPSC*(float)(db>>24)              + bf2f(cp[7]);
      float* er = outE + (size_t)src*DD + c8*8;
      *(float4*)er = e0;
      *(float4*)(er+4) = e1;
    }
  }
  // ---- stage2 MFMA: P = Ct[:, 0:128] @ W1 (A in-place, stride STRA) ----
  #pragma unroll
  for (int ntl = 0; ntl < 2; ++ntl)
    #pragma unroll
    for (int kt = 0; kt < 4; ++kt)
      bfrag[ntl][kt] = *(const bf16x8*)(W1swz + ((size_t)(kt*8 + w*2 + ntl)*64 + l)*8);
  #pragma unroll
  for (int rt = 0; rt < 4; ++rt) {
    acc[rt][0] = (f32x4){0.f,0.f,0.f,0.f};
    acc[rt][1] = (f32x4){0.f,0.f,0.f,0.f};
  }
  #pragma unroll
  for (int kt = 0; kt < 4; ++kt)
    #pragma unroll
    for (int rt = 0; rt < 4; ++rt) {
      bf16x8 af = *(const bf16x8*)&Ct[(rt*16 + m)*STRA + kt*32 + q*8];
      acc[rt][0] = __builtin_amdgcn_mfma_f32_16x16x32_bf16(af, bfrag[0][kt], acc[rt][0], 0, 0, 0);
      acc[rt][1] = __builtin_amdgcn_mfma_f32_16x16x32_bf16(af, bfrag[1][kt], acc[rt][1], 0, 0, 0);
    }
  // ---- b1 + validity + BN partials (per-wave disjoint cols; red in As1) ----
  float* red = (float*)As1;   // [type(2)][seg(2)][128 cols] = 2KB
  #pragma unroll
  for (int ntl = 0; ntl < 2; ++ntl) {
    float bv = b1[cbase + ntl*16];
    float s0 = 0.f, s1 = 0.f, q0 = 0.f, q1 = 0.f;
    #pragma unroll
    for (int rt = 0; rt < 4; ++rt)
      #pragma unroll
      for (int i = 0; i < 4; ++i) {
        int src = r0 + (((rt*16 + q*4 + i)) & 31);
        float v = (src < N) ? (acc[rt][ntl][i] + bv) : 0.f;
        acc[rt][ntl][i] = v;
        if (rt < 2) { s0 += v; q0 += v*v; } else { s1 += v; q1 += v*v; }
      }
    s0 += __shfl_xor(s0, 16); s0 += __shfl_xor(s0, 32);
    s1 += __shfl_xor(s1, 16); s1 += __shfl_xor(s1, 32);
    q0 += __shfl_xor(q0, 16); q0 += __shfl_xor(q0, 32);
    q1 += __shfl_xor(q1, 16); q1 += __shfl_xor(q1, 32);
    if (l < 16) {
      int c = cbase + ntl*16;     // l<16 => m==l
      red[          c] = s0;
      red[128     + c] = s1;
      red[256     + c] = q0;
      red[256+128 + c] = q1;
    }
  }
  __syncthreads();                                        // (5)
  {
    int type = tid >> 7, col = tid & 127;
    float v0 = red[type*256 + col];          // seg0
    float v1 = red[type*256 + 128 + col];    // seg1
    partial[((size_t)0*NB + blockIdx.x)*256 + tid] = v0;
    partial[((size_t)1*NB + blockIdx.x)*256 + tid] = v1;
  }
  // ---- P-tile (bf16) into Ct: all Ct reads completed before sync(5) ----
  #pragma unroll
  for (int ntl = 0; ntl < 2; ++ntl)
    #pragma unroll
    for (int rt = 0; rt < 4; ++rt)
      #pragma unroll
      for (int i = 0; i < 4; ++i)
        Ct[(rt*16 + q*4 + i)*STRA + cbase + ntl*16] = f2bf(acc[rt][ntl][i]);
  __syncthreads();                                        // (6)
  // ---- P write: rows 0-31 -> Px, rows 32-63 -> Py ----
  {
    const int ar = tid >> 2, p = tid & 3;
    const int src = r0 + (ar & 31);
    if (src < N) {
      const u16* sp = &Ct[ar*STRA + p*32];
      u16* dp = ((ar >> 5) ? Py : Px) + (size_t)src*DD + p*32;
      #pragma unroll
      for (int i = 0; i < 4; ++i)
        *(bf16x8*)(dp + i*8) = *(const bf16x8*)(sp + i*8);
    }
  }
}

// K5b: reduce per-block partials into stats (few atomics).
__global__ __launch_bounds__(256) void k5b_stats(
    const float* __restrict__ partial, float* __restrict__ stats, int nb)
{
  int seg = blockIdx.y, chunk = blockIdx.x, t = threadIdx.x;
  int per = (nb + gridDim.x - 1) / gridDim.x;
  int lo = chunk*per, hi = lo+per; if (hi > nb) hi = nb;
  float s = 0.f;
  const float* p = partial + (size_t)seg*nb*256;
  for (int i = lo; i < hi; ++i) s += p[(size_t)i*256 + t];
  atomicAdd(&stats[seg*256 + t], s);
}

// K6: BN+PReLU (bf16 P) -> MFMA GEMM2 (+b2, wave-per-column-slice, B-frags
// hoisted) -> parallel per-row BYOL cosine -> 1 atomic/block. NO device fence.
__global__ __launch_bounds__(256) void k6_gemm_loss(
    const u16* __restrict__ Px, const u16* __restrict__ Py,
    const u16* __restrict__ AGGb, const float* __restrict__ stats,
    const float* __restrict__ gamma, const float* __restrict__ beta,
    const float* __restrict__ aP, const u16* __restrict__ W2swz,
    const float* __restrict__ b2, float* __restrict__ gloss, int N)
{
  __shared__ __align__(16) float Cs[64*STRCF];   // 33792B; aliased as As (17408B)
  u16* As = (u16*)Cs;
  __shared__ float s1s[128], s2s[128];
  __shared__ float gred[4];
  const int tid = threadIdx.x;
  const int seg = blockIdx.y;
  const u16* __restrict__ P = seg ? Py : Px;
  const int toff = seg ? 0 : 128;
  const float invN = 1.f / (float)N;
  if (tid < 128) {
    float mu = stats[seg*256 + tid] * invN;
    float var = stats[seg*256 + 128 + tid] * invN - mu*mu;
    float rstd = rsqrtf(var + 1e-5f);
    float s1 = rstd * gamma[tid];
    s1s[tid] = s1;
    s2s[tid] = beta[tid] - mu*s1;
  }
  const float alpha = aP[0];
  const int r0 = blockIdx.x * 64;
  __syncthreads();
  #pragma unroll
  for (int i = 0; i < 4; ++i) {
    int f = tid + 256*i;
    int row = f >> 4, c8 = f & 15;
    int r = r0 + row;
    bf16x8 ch = {0,0,0,0,0,0,0,0};
    if (r < N) ch = *(const bf16x8*)(P + (size_t)r*DD + c8*8);
    bf16x8 a;
    #pragma unroll
    for (int t2 = 0; t2 < 8; ++t2) {
      int colc = c8*8 + t2;
      float hv = bf2f((u16)ch[t2]);
      float hn = hv*s1s[colc] + s2s[colc];
      hn = hn >= 0.f ? hn : alpha*hn;
      a[t2] = (short)f2bf(hn);
    }
    *(bf16x8*)&As[row*STRA + c8*8] = a;
  }
  __syncthreads();
  const int w = tid >> 6, l = tid & 63;
  const int m = l & 15, q = l >> 4;
  const int cbase = w*32 + m;
  f32x4 acc[4][2];
  bf16x8 bfrag[2][4];
  #pragma unroll
  for (int ntl = 0; ntl < 2; ++ntl)
    #pragma unroll
    for (int kt = 0; kt < 4; ++kt)
      bfrag[ntl][kt] = *(const bf16x8*)(W2swz + ((size_t)(kt*8 + w*2 + ntl)*64 + l)*8);
  #pragma unroll
  for (int rt = 0; rt < 4; ++rt) {
    acc[rt][0] = (f32x4){0.f,0.f,0.f,0.f};
    acc[rt][1] = (f32x4){0.f,0.f,0.f,0.f};
  }
  #pragma unroll
  for (int kt = 0; kt < 4; ++kt)
    #pragma unroll
    for (int rt = 0; rt < 4; ++rt) {
      bf16x8 af = *(const bf16x8*)&As[(rt*16 + m)*STRA + kt*32 + q*8];
      acc[rt][0] = __builtin_amdgcn_mfma_f32_16x16x32_bf16(af, bfrag[0][kt], acc[rt][0], 0, 0, 0);
      acc[rt][1] = __builtin_amdgcn_mfma_f32_16x16x32_bf16(af, bfrag[1][kt], acc[rt][1], 0, 0, 0);
    }
  __syncthreads();                  // As dead; Cs writes follow (aliased)
  #pragma unroll
  for (int ntl = 0; ntl < 2; ++ntl) {
    float bv = b2[cbase + ntl*16];
    #pragma unroll
    for (int rt = 0; rt < 4; ++rt)
      #pragma unroll
      for (int i = 0; i < 4; ++i)
        Cs[(rt*16 + q*4 + i)*STRCF + cbase + ntl*16] = acc[rt][ntl][i] + bv;
  }
  __syncthreads();
  // Parallel BYOL cosine: 4 lanes per row; xor1+xor2 completes row sums;
  // xor4..32 sums 16 distinct rows once per qq-group (no /4 — R2 lesson).
  {
    const int rt = tid >> 2, qq = tid & 3;
    const int r = r0 + rt;
    float pp = 0.f, tt = 0.f, pt = 0.f;
    if (r < N) {
      const float* prow = &Cs[rt*STRCF + qq*32];
      const u16* trow = AGGb + (size_t)r*256 + toff + qq*32;
      #pragma unroll
      for (int i = 0; i < 4; ++i) {
        float4 pa = *(const float4*)(prow + i*8);
        float4 pb = *(const float4*)(prow + i*8 + 4);
        uint4 twv = *(const uint4*)(trow + i*8);
        float t0=bflo(twv.x), t1=bfhi(twv.x), t2=bflo(twv.y), t3=bfhi(twv.y);
        float t4=bflo(twv.z), t5=bfhi(twv.z), t6=bflo(twv.w), t7=bfhi(twv.w);
        pp += pa.x*pa.x + pa.y*pa.y + pa.z*pa.z + pa.w*pa.w
            + pb.x*pb.x + pb.y*pb.y + pb.z*pb.z + pb.w*pb.w;
        tt += t0*t0 + t1*t1 + t2*t2 + t3*t3 + t4*t4 + t5*t5 + t6*t6 + t7*t7;
        pt += pa.x*t0 + pa.y*t1 + pa.z*t2 + pa.w*t3
            + pb.x*t4 + pb.y*t5 + pb.z*t6 + pb.w*t7;
      }
    }
    pp += __shfl_xor(pp, 1); pp += __shfl_xor(pp, 2);
    tt += __shfl_xor(tt, 1); tt += __shfl_xor(tt, 2);
    pt += __shfl_xor(pt, 1); pt += __shfl_xor(pt, 2);
    float lsum = (r < N) ? (2.f - 2.f * pt * rsqrtf(pp * tt)) : 0.f;
    lsum += __shfl_xor(lsum, 4);  lsum += __shfl_xor(lsum, 8);
    lsum += __shfl_xor(lsum, 16); lsum += __shfl_xor(lsum, 32);
    if (l == 0) gred[w] = lsum;
  }
  __syncthreads();
  if (tid == 0) atomicAdd(gloss, gred[0]+gred[1]+gred[2]+gred[3]);
}

__global__ void k7_loss(const float* __restrict__ gloss, float* __restrict__ out, int N, int total)
{
  out[total] = gloss[0] / (float)N;
}

extern "C" void kernel_launch(void* const* d_in, const int* in_sizes, int n_in,
                              void* d_out, int out_size, void* d_ws, size_t ws_size,
                              hipStream_t stream)
{
  const float* x    = (const float*)d_in[0];
  const float* perb = (const float*)d_in[1];
  const int*   erow = (const int*)d_in[2];
  const int*   ecol = (const int*)d_in[3];
  const float* eval_= (const float*)d_in[4];
  const float* W    = (const float*)d_in[5];
  const float* b    = (const float*)d_in[6];
  const float* Wt   = (const float*)d_in[7];
  const float* bt   = (const float*)d_in[8];
  const float* W1   = (const float*)d_in[9];
  const float* b1   = (const float*)d_in[10];
  const float* gam  = (const float*)d_in[11];
  const float* bet  = (const float*)d_in[12];
  const float* aP   = (const float*)d_in[13];
  const float* W2   = (const float*)d_in[14];
  const float* b2   = (const float*)d_in[15];
  const int N = in_sizes[0] / DD;
  const int E = in_sizes[2];
  const int NB4 = (N + 31)/32;
  const int NB5 = (N + 63)/64;

  char* ws = (char*)d_ws;
  size_t off = 0;
  auto alloc = [&](size_t bytes) -> void* {
    void* p = ws + off;
    off += (bytes + 255) & ~(size_t)255;
    return p;
  };
  u16*   AGGb = (u16*)  alloc((size_t)N*256*sizeof(u16));   // 25.6 MB [s1|s3]
  u8*    Tg   = (u8*)   alloc((size_t)N*384);               // 19.2 MB gather table
  u16*   T2   = (u16*)  alloc((size_t)N*256*sizeof(u16));   // 25.6 MB
  u16*   Px   = (u16*)  alloc((size_t)N*DD*sizeof(u16));    // 12.8 MB
  u16*   Py   = (u16*)  alloc((size_t)N*DD*sizeof(u16));    // 12.8 MB
  int*   deg  = (int*)  alloc((size_t)N*sizeof(int));
  float* stats= (float*)alloc(512*sizeof(float));
  float* gloss= (float*)alloc(256);
  int*   ovfc = (int*)((char*)gloss + 64);
  u32*   perm = (u32*)  alloc((size_t)N*CAP*sizeof(u32));   // 12.8 MB packed
  int*   ovf  = (int*)  alloc(4096*sizeof(int));
  u16*   Bswz = (u16*)  alloc(32768*sizeof(u16));
  u16*   W1swz= (u16*)  alloc(16384*sizeof(u16));
  u16*   W2swz= (u16*)  alloc(16384*sizeof(u16));
  float* partial = (float*)alloc((size_t)2*NB4*256*sizeof(float)); // 3.2 MB
  if (ws_size < off) return;

  kU_init<<<(N*32 + 255)/256, 256, 0, stream>>>(x, perb, W, Wt, W1, W2,
                                                Tg, Bswz, W1swz, W2swz,
                                                deg, stats, gloss, N);
  k2_bucket<<<(E + 255)/256, 256, 0, stream>>>(erow, ecol, eval_, E, deg, perm, ovfc, ovf);
  k3_spmm<<<(N + 3)/4, 256, 0, stream>>>(perm, deg, Tg, T2, N);
  k3b_ovf<<<1, 256, 0, stream>>>(erow, ecol, eval_, ovfc, ovf, Tg, T2);
  k4_gemm<<<NB4, 256, 0, stream>>>(T2, Bswz, W1swz, b, bt, b1, Tg,
                                   AGGb, (float*)d_out, Px, Py, partial, N, NB4);
  k5b_stats<<<dim3(16, 2), 256, 0, stream>>>(partial, stats, NB4);
  k6_gemm_loss<<<dim3(NB5, 2), 256, 0, stream>>>(Px, Py, AGGb, stats, gam, bet, aP,
                                                 W2swz, b2, gloss, N);
  k7_loss<<<1, 1, 0, stream>>>(gloss, (float*)d_out, N, N*DD);
}

// Round 8
// 299.249 us; speedup vs baseline: 1.1110x; 1.0017x over previous
//
#include <hip/hip_runtime.h>
#include <hip/hip_fp16.h>
#include <stdint.h>

typedef unsigned short u16;
typedef unsigned int u32;
typedef unsigned char u8;
typedef __attribute__((ext_vector_type(8))) short bf16x8;
typedef __attribute__((ext_vector_type(4))) short bf16x4;
typedef __attribute__((ext_vector_type(4))) float f32x4;

#define DD 128
#define CAP 64     // Poisson(16): P(deg>64) ~ 1e-20; overflow path still correct
#define STRA 136   // A/C half-tile LDS stride (u16): 272B rows, 16B-aligned
#define STRCF 132  // k6 f32 C-tile stride
#define PSC 256.f  // perb int8 scale: q = rint(perb*256), |err| <= 0.002
#define IPSC (1.f/256.f)
#define NPART 8    // k2 row partitions (XCD-affine via blockIdx&7)

__device__ __forceinline__ float bflo(u32 u){ return __uint_as_float(u<<16); }
__device__ __forceinline__ float bfhi(u32 u){ return __uint_as_float(u & 0xffff0000u); }
__device__ __forceinline__ float bf2f(u16 u){ return __uint_as_float(((u32)u)<<16); }
__device__ __forceinline__ u16 f2bf(float f){
  u32 u = __float_as_uint(f);
  return (u16)((u + 0x7fffu + ((u>>16)&1u)) >> 16);   // RNE
}

// Tg row (384B): 32 chunks of 12B; chunk hl = [4x bf16 x (8B) | 4x int8 perb (4B)]
#define FMAXP(g, vv, vqv) do { \
    ax[0] += (vv)*bflo((g).x); ax[1] += (vv)*bfhi((g).x); \
    ax[2] += (vv)*bflo((g).y); ax[3] += (vv)*bfhi((g).y); \
    int d_ = (int)(g).z; \
    ap[0] += (vqv)*(float)(signed char)(d_); \
    ap[1] += (vqv)*(float)(signed char)(d_>>8); \
    ap[2] += (vqv)*(float)(signed char)(d_>>16); \
    ap[3] += (vqv)*(float)(d_>>24); } while(0)

// kU: fused init. (a) zero control region (COMPUTE kernel, never SDMA/memset —
// graph replay ordering), (b) pre-swizzle weights into MFMA B-fragment order,
// (c) build gather table Tg (bf16 x + int8 perb, 384B/row).
__global__ __launch_bounds__(256) void kU_init(
    const float* __restrict__ x, const float* __restrict__ perb,
    const float* __restrict__ W, const float* __restrict__ Wt,
    const float* __restrict__ W1, const float* __restrict__ W2,
    u8* __restrict__ Tg, u16* __restrict__ Bswz,
    u16* __restrict__ W1swz, u16* __restrict__ W2swz,
    int* __restrict__ deg, float* __restrict__ stats,
    float* __restrict__ gbuf, int N)
{
  int f = blockIdx.x*256 + threadIdx.x;
  if (f < N) deg[f] = 0;
  if (f < 512) stats[f] = 0.f;
  if (f < 64) gbuf[f] = 0.f;   // covers gloss + ovfc (256B block)
  if (f < 65536) {
    int idx = f;
    if (idx < 32768) {
      int j = idx & 7, lane = (idx>>3)&63, nt = (idx>>9)&15, kt = idx>>13;
      int k = kt*32 + (lane>>4)*8 + j, n = nt*16 + (lane&15);
      float v = (n < DD) ? W[k*DD + n] : Wt[k*DD + (n-DD)];
      Bswz[idx] = f2bf(v);
    } else {
      int t = idx - 32768;
      int which = t >> 14; t &= 16383;
      int j = t & 7, lane = (t>>3)&63, nt = (t>>9)&7, kt = (t>>12)&3;
      int k = kt*32 + (lane>>4)*8 + j, n = nt*16 + (lane&15);
      const float* __restrict__ src = which ? W2 : W1;
      u16* __restrict__ dst = which ? W2swz : W1swz;
      dst[t] = f2bf(src[k*DD + n]);
    }
  }
  if (f < N*32) {
    int r = f >> 5, hl = f & 31;
    float4 xa = *(const float4*)(x    + (size_t)r*DD + hl*4);
    float4 pa = *(const float4*)(perb + (size_t)r*DD + hl*4);
    u32 d0 = (u32)f2bf(xa.x) | ((u32)f2bf(xa.y) << 16);
    u32 d1 = (u32)f2bf(xa.z) | ((u32)f2bf(xa.w) << 16);
    int q0 = (int)rintf(pa.x*PSC); q0 = q0 < -127 ? -127 : (q0 > 127 ? 127 : q0);
    int q1 = (int)rintf(pa.y*PSC); q1 = q1 < -127 ? -127 : (q1 > 127 ? 127 : q1);
    int q2 = (int)rintf(pa.z*PSC); q2 = q2 < -127 ? -127 : (q2 > 127 ? 127 : q2);
    int q3 = (int)rintf(pa.w*PSC); q3 = q3 < -127 ? -127 : (q3 > 127 ? 127 : q3);
    u32 d2 = (u32)(q0 & 0xff) | ((u32)(q1 & 0xff) << 8)
           | ((u32)(q2 & 0xff) << 16) | ((u32)(q3 & 0xff) << 24);
    uint3 o; o.x = d0; o.y = d1; o.z = d2;
    *(uint3*)(Tg + (size_t)r*384 + hl*12) = o;
  }
}

// K2 (R8 partitioned binning): part = blockIdx&7 — under default round-robin
// dispatch all blocks of a partition land on ONE XCD, so the partition's 1.6MB
// perm slice stays resident in that L2 and scattered 4B writes fully merge
// before writeback (R7 counter: WRITE_SIZE 48MB = 64B/edge write-amp).
// Each block scans a contiguous edge chunk, keeps rows in its partition.
// Correctness independent of the blockIdx->XCD mapping.
__global__ __launch_bounds__(256) void k2_bucket(
    const int* __restrict__ row, const int* __restrict__ col,
    const float* __restrict__ val, int E, int* __restrict__ deg,
    u32* __restrict__ perm, int* __restrict__ ovfc, int* __restrict__ ovf,
    int rowsPerPart)
{
  const int part = blockIdx.x & (NPART-1);
  const int chunk = blockIdx.x >> 3;
  const int nchunk = gridDim.x >> 3;
  const int lo = part * rowsPerPart;
  const int hi = lo + rowsPerPart;
  int per = (E + nchunk - 1) / nchunk;
  int e0 = chunk * per;
  int e1 = e0 + per; if (e1 > E) e1 = E;
  for (int e = e0 + threadIdx.x; e < e1; e += 256) {
    int r = row[e];
    if (r < lo || r >= hi) continue;
    int slot = atomicAdd(&deg[r], 1);
    if (slot < CAP) {
      u32 pk = (u32)(col[e] & 0xffff)
             | ((u32)__half_as_ushort(__float2half(val[e])) << 16);
      perm[(size_t)r*CAP + slot] = pk;
    }
    else { int oi = atomicAdd(ovfc, 1); if (oi < 4096) ovf[oi] = e; }
  }
}

// K3: one wave per row; 384B/edge gathers (12B/lane dwordx3), two wave-halves
// process even/odd edges. Random-gather memory-pattern bound.
__global__ __launch_bounds__(256) void k3_spmm(
    const u32* __restrict__ perm, const int* __restrict__ deg,
    const u8* __restrict__ Tg, u16* __restrict__ T2, int N)
{
  int row = blockIdx.x*4 + (threadIdx.x >> 6);
  int l = threadIdx.x & 63;
  if (row >= N) return;
  int dg = deg[row];
  dg = dg < 0 ? 0 : (dg > CAP ? CAP : dg);       // defensive clamp
  const int half = l >> 5, hl = l & 31;
  const int loff = hl * 12;                       // byte offset in 384B row
  float ax[4] = {0.f,0.f,0.f,0.f};
  float ap[4] = {0.f,0.f,0.f,0.f};
  for (int base = 0; base < dg; base += 64) {
    u32 pk = 0;                                   // pad: c=0, v=0 (harmless gather)
    if (base + l < dg) pk = perm[(size_t)row*CAP + base + l];
    int mm = dg - base; if (mm > 64) mm = 64;
    int kmax = (mm + 1) & ~1;                     // round up to even (pad v=0)
    int j = 0;
    for (; j + 8 <= kmax; j += 8) {
      u32 p0 = (u32)__shfl((int)pk, j + half);
      u32 p1 = (u32)__shfl((int)pk, j + 2 + half);
      u32 p2 = (u32)__shfl((int)pk, j + 4 + half);
      u32 p3 = (u32)__shfl((int)pk, j + 6 + half);
      int c0 = p0 & 0xffff; c0 = (c0 < N) ? c0 : 0;
      int c1 = p1 & 0xffff; c1 = (c1 < N) ? c1 : 0;
      int c2 = p2 & 0xffff; c2 = (c2 < N) ? c2 : 0;
      int c3 = p3 & 0xffff; c3 = (c3 < N) ? c3 : 0;
      float v0 = __half2float(__ushort_as_half((u16)(p0 >> 16)));
      float v1 = __half2float(__ushort_as_half((u16)(p1 >> 16)));
      float v2 = __half2float(__ushort_as_half((u16)(p2 >> 16)));
      float v3 = __half2float(__ushort_as_half((u16)(p3 >> 16)));
      uint3 g0 = *(const uint3*)(Tg + (size_t)c0*384 + loff);
      uint3 g1 = *(const uint3*)(Tg + (size_t)c1*384 + loff);
      uint3 g2 = *(const uint3*)(Tg + (size_t)c2*384 + loff);
      uint3 g3 = *(const uint3*)(Tg + (size_t)c3*384 + loff);
      float vq0 = v0*IPSC, vq1 = v1*IPSC, vq2 = v2*IPSC, vq3 = v3*IPSC;
      FMAXP(g0, v0, vq0); FMAXP(g1, v1, vq1);
      FMAXP(g2, v2, vq2); FMAXP(g3, v3, vq3);
    }
    for (; j < kmax; j += 2) {
      u32 p0 = (u32)__shfl((int)pk, j + half);
      int c0 = p0 & 0xffff; c0 = (c0 < N) ? c0 : 0;
      float v0 = __half2float(__ushort_as_half((u16)(p0 >> 16)));
      uint3 g0 = *(const uint3*)(Tg + (size_t)c0*384 + loff);
      float vq0 = v0*IPSC;
      FMAXP(g0, v0, vq0);
    }
  }
  // combine even/odd-edge partials across halves
  #pragma unroll
  for (int i = 0; i < 4; ++i) {
    ax[i] += __shfl_xor(ax[i], 32);
    ap[i] += __shfl_xor(ap[i], 32);
  }
  // T2 row = [aggx1 (128) | aggx2=aggx1+aggp (128)]; half0 writes x1, half1 x2.
  bf16x4 ob;
  #pragma unroll
  for (int i = 0; i < 4; ++i) {
    float o = half ? (ax[i] + ap[i]) : ax[i];
    ob[i] = (short)f2bf(o);
  }
  *(bf16x4*)(T2 + (size_t)row*256 + half*128 + hl*4) = ob;  // 64 lanes x 8B
}

// K3b: overflow fallback (expected empty) — serial RMW on T2 (raw edges).
__global__ __launch_bounds__(256) void k3b_ovf(
    const int* __restrict__ rowI, const int* __restrict__ colI,
    const float* __restrict__ val, const int* __restrict__ ovfc,
    const int* __restrict__ ovf, const u8* __restrict__ Tg,
    u16* __restrict__ T2)
{
  int n = *ovfc; if (n > 4096) n = 4096;
  for (int i = 0; i < n; ++i) {
    int e = ovf[i];
    int r = rowI[e], c = colI[e];
    float v = val[e];
    int d = threadIdx.x;           // 256 threads cover the 256-wide row
    int dl = d & 127;
    const u8* tgc = Tg + (size_t)c*384 + (dl>>2)*12;
    float xv = bf2f(*(const u16*)(tgc + (dl&3)*2));
    float add = v * xv;
    if (d >= 128) {
      int qb = (int)(signed char)tgc[8 + (dl&3)];
      add = v * (xv + (float)qb * IPSC);
    }
    u16* p = &T2[(size_t)r*256 + d];
    *p = f2bf(bf2f(*p) + add);
  }
}

// K4 (fused k4+k5, wave-per-column-slice): wave w owns cols w*32..w*32+31
// over ALL 64 rows; 8 B-fragments hoisted into registers per pass.
//   passA: cols 128-255 -> Ct=[s1|s3] -> AGGb
//   passB: cols 0-127 + bias -> Ct=[s0|s2+b] -> embed; stage2 A-operand
//   stage2: P = Ct @ W1 + b1 -> BN partials (per-wave disjoint cols) + Px/Py
__global__ __launch_bounds__(256, 4) void k4_gemm(
    const u16* __restrict__ T2, const u16* __restrict__ Bswz,
    const u16* __restrict__ W1swz,
    const float* __restrict__ b, const float* __restrict__ bt,
    const float* __restrict__ b1, const u8* __restrict__ Tg,
    u16* __restrict__ AGGb, float* __restrict__ outE,
    u16* __restrict__ Px, u16* __restrict__ Py,
    float* __restrict__ partial, int N, int NB)
{
  __shared__ __align__(16) u16 As1[64*STRA];   // 17408B; later red (f32[512])
  __shared__ __align__(16) u16 Ct[64*STRA];    // 17408B half C-tile (u16/bf16)
  const int tid = threadIdx.x;
  const int r0 = blockIdx.x * 32;
  // ---- load A (64 rows: 0-31 = aggx1, 32-63 = aggx2) ----
  #pragma unroll
  for (int i = 0; i < 4; ++i) {
    int f = tid + 256*i;            // 1024 chunks: 64 A-rows x 16 chunks of 8
    int row = f >> 4, c8 = f & 15;
    int r = r0 + (row & 31);
    bf16x8 ch = {0,0,0,0,0,0,0,0};
    if (r < N) ch = *(const bf16x8*)(T2 + (size_t)r*256 + (row>>5)*128 + c8*8);
    *(bf16x8*)&As1[row*STRA + c8*8] = ch;
  }
  __syncthreads();                                        // (1)
  const int w = tid >> 6, l = tid & 63;
  const int m = l & 15, q = l >> 4;
  const int cbase = w*32 + m;        // this wave's column base (+ntl*16)
  f32x4 acc[4][2];
  bf16x8 bfrag[2][4];
  // ---- stage1 pass A: global cols 128..255 ([s1|s3]) ----
  #pragma unroll
  for (int ntl = 0; ntl < 2; ++ntl)
    #pragma unroll
    for (int kt = 0; kt < 4; ++kt)
      bfrag[ntl][kt] = *(const bf16x8*)(Bswz + ((size_t)(kt*16 + 8 + w*2 + ntl)*64 + l)*8);
  #pragma unroll
  for (int rt = 0; rt < 4; ++rt) {
    acc[rt][0] = (f32x4){0.f,0.f,0.f,0.f};
    acc[rt][1] = (f32x4){0.f,0.f,0.f,0.f};
  }
  #pragma unroll
  for (int kt = 0; kt < 4; ++kt)
    #pragma unroll
    for (int rt = 0; rt < 4; ++rt) {
      bf16x8 af = *(const bf16x8*)&As1[(rt*16 + m)*STRA + kt*32 + q*8];
      acc[rt][0] = __builtin_amdgcn_mfma_f32_16x16x32_bf16(af, bfrag[0][kt], acc[rt][0], 0, 0, 0);
      acc[rt][1] = __builtin_amdgcn_mfma_f32_16x16x32_bf16(af, bfrag[1][kt], acc[rt][1], 0, 0, 0);
    }
  #pragma unroll
  for (int ntl = 0; ntl < 2; ++ntl) {
    float bv = bt[cbase + ntl*16];
    #pragma unroll
    for (int rt = 0; rt < 4; ++rt)
      #pragma unroll
      for (int i = 0; i < 4; ++i)
        Ct[(rt*16 + q*4 + i)*STRA + cbase + ntl*16] = f2bf(acc[rt][ntl][i] + bv);
  }
  __syncthreads();                                        // (2)
  // ---- AGGb write: [s1|s3] (rows<32 -> s1 @0, rows>=32 -> s3 @128) ----
  {
    const int ar = tid >> 2, p = tid & 3;
    const int src = r0 + (ar & 31);
    if (src < N) {
      u16* dp = AGGb + (size_t)src*256 + (ar>>5)*128 + p*32;
      const u16* sp = &Ct[ar*STRA + p*32];
      #pragma unroll
      for (int i = 0; i < 4; ++i)
        *(bf16x8*)(dp + i*8) = *(const bf16x8*)(sp + i*8);
    }
  }
  __syncthreads();                                        // (3) Ct reads done
  // ---- stage1 pass B: global cols 0..127 ([s0|s2] + bias) ----
  #pragma unroll
  for (int ntl = 0; ntl < 2; ++ntl)
    #pragma unroll
    for (int kt = 0; kt < 4; ++kt)
      bfrag[ntl][kt] = *(const bf16x8*)(Bswz + ((size_t)(kt*16 + w*2 + ntl)*64 + l)*8);
  #pragma unroll
  for (int rt = 0; rt < 4; ++rt) {
    acc[rt][0] = (f32x4){0.f,0.f,0.f,0.f};
    acc[rt][1] = (f32x4){0.f,0.f,0.f,0.f};
  }
  #pragma unroll
  for (int kt = 0; kt < 4; ++kt)
    #pragma unroll
    for (int rt = 0; rt < 4; ++rt) {
      bf16x8 af = *(const bf16x8*)&As1[(rt*16 + m)*STRA + kt*32 + q*8];
      acc[rt][0] = __builtin_amdgcn_mfma_f32_16x16x32_bf16(af, bfrag[0][kt], acc[rt][0], 0, 0, 0);
      acc[rt][1] = __builtin_amdgcn_mfma_f32_16x16x32_bf16(af, bfrag[1][kt], acc[rt][1], 0, 0, 0);
    }
  #pragma unroll
  for (int ntl = 0; ntl < 2; ++ntl) {
    float bv = b[cbase + ntl*16];
    #pragma unroll
    for (int rt = 0; rt < 4; ++rt)
      #pragma unroll
      for (int i = 0; i < 4; ++i)
        Ct[(rt*16 + q*4 + i)*STRA + cbase + ntl*16] = f2bf(acc[rt][ntl][i] + bv);
  }
  __syncthreads();                                        // (4)
  // ---- embed = x + perb + s2 (Ct rows 32-63, bias incl.); x,perb from Tg ----
  #pragma unroll
  for (int i = 0; i < 2; ++i) {
    int f = tid + 256*i;            // 512 chunks: 32 rows x 16 chunks of 8
    int rr = f >> 4, c8 = f & 15;
    int src = r0 + rr;
    if (src < N) {
      const u16* cp = &Ct[(32+rr)*STRA + c8*8];
      const u8* tg = Tg + (size_t)src*384 + c8*24;   // two 12B chunks
      uint3 ga = *(const uint3*)tg;
      uint3 gb = *(const uint3*)(tg + 12);
      int da = (int)ga.z, db = (int)gb.z;
      float4 e0, e1;
      e0.x = bflo(ga.x) + IPSC*(float)(signed char)(da)     + bf2f(cp[0]);
      e0.y = bfhi(ga.x) + IPSC*(float)(signed char)(da>>8)  + bf2f(cp[1]);
      e0.z = bflo(ga.y) + IPSC*(float)(signed char)(da>>16) + bf2f(cp[2]);
      e0.w = bfhi(ga.y) + IPSC*(float)(da>>24)              + bf2f(cp[3]);
      e1.x = bflo(gb.x) + IPSC*(float)(signed char)(db)     + bf2f(cp[4]);
      e1.y = bfhi(gb.x) + IPSC*(float)(signed char)(db>>8)  + bf2f(cp[5]);
      e1.z = bflo(gb.y) + IPSC*(float)(signed char)(db>>16) + bf2f(cp[6]);
      e1.w = bfhi(gb.y) + IPSC*(float)(db>>24)              + bf2f(cp[7]);
      float* er = outE + (size_t)src*DD + c8*8;
      *(float4*)er = e0;
      *(float4*)(er+4) = e1;
    }
  }
  // ---- stage2 MFMA: P = Ct[:, 0:128] @ W1 (A in-place, stride STRA) ----
  #pragma unroll
  for (int ntl = 0; ntl < 2; ++ntl)
    #pragma unroll
    for (int kt = 0; kt < 4; ++kt)
      bfrag[ntl][kt] = *(const bf16x8*)(W1swz + ((size_t)(kt*8 + w*2 + ntl)*64 + l)*8);
  #pragma unroll
  for (int rt = 0; rt < 4; ++rt) {
    acc[rt][0] = (f32x4){0.f,0.f,0.f,0.f};
    acc[rt][1] = (f32x4){0.f,0.f,0.f,0.f};
  }
  #pragma unroll
  for (int kt = 0; kt < 4; ++kt)
    #pragma unroll
    for (int rt = 0; rt < 4; ++rt) {
      bf16x8 af = *(const bf16x8*)&Ct[(rt*16 + m)*STRA + kt*32 + q*8];
      acc[rt][0] = __builtin_amdgcn_mfma_f32_16x16x32_bf16(af, bfrag[0][kt], acc[rt][0], 0, 0, 0);
      acc[rt][1] = __builtin_amdgcn_mfma_f32_16x16x32_bf16(af, bfrag[1][kt], acc[rt][1], 0, 0, 0);
    }
  // ---- b1 + validity + BN partials (per-wave disjoint cols; red in As1) ----
  float* red = (float*)As1;   // [type(2)][seg(2)][128 cols] = 2KB
  #pragma unroll
  for (int ntl = 0; ntl < 2; ++ntl) {
    float bv = b1[cbase + ntl*16];
    float s0 = 0.f, s1 = 0.f, q0 = 0.f, q1 = 0.f;
    #pragma unroll
    for (int rt = 0; rt < 4; ++rt)
      #pragma unroll
      for (int i = 0; i < 4; ++i) {
        int src = r0 + (((rt*16 + q*4 + i)) & 31);
        float v = (src < N) ? (acc[rt][ntl][i] + bv) : 0.f;
        acc[rt][ntl][i] = v;
        if (rt < 2) { s0 += v; q0 += v*v; } else { s1 += v; q1 += v*v; }
      }
    s0 += __shfl_xor(s0, 16); s0 += __shfl_xor(s0, 32);
    s1 += __shfl_xor(s1, 16); s1 += __shfl_xor(s1, 32);
    q0 += __shfl_xor(q0, 16); q0 += __shfl_xor(q0, 32);
    q1 += __shfl_xor(q1, 16); q1 += __shfl_xor(q1, 32);
    if (l < 16) {
      int c = cbase + ntl*16;     // l<16 => m==l
      red[          c] = s0;
      red[128     + c] = s1;
      red[256     + c] = q0;
      red[256+128 + c] = q1;
    }
  }
  __syncthreads();                                        // (5)
  {
    int type = tid >> 7, col = tid & 127;
    float v0 = red[type*256 + col];          // seg0
    float v1 = red[type*256 + 128 + col];    // seg1
    partial[((size_t)0*NB + blockIdx.x)*256 + tid] = v0;
    partial[((size_t)1*NB + blockIdx.x)*256 + tid] = v1;
  }
  // ---- P-tile (bf16) into Ct: all Ct reads completed before sync(5) ----
  #pragma unroll
  for (int ntl = 0; ntl < 2; ++ntl)
    #pragma unroll
    for (int rt = 0; rt < 4; ++rt)
      #pragma unroll
      for (int i = 0; i < 4; ++i)
        Ct[(rt*16 + q*4 + i)*STRA + cbase + ntl*16] = f2bf(acc[rt][ntl][i]);
  __syncthreads();                                        // (6)
  // ---- P write: rows 0-31 -> Px, rows 32-63 -> Py ----
  {
    const int ar = tid >> 2, p = tid & 3;
    const int src = r0 + (ar & 31);
    if (src < N) {
      const u16* sp = &Ct[ar*STRA + p*32];
      u16* dp = ((ar >> 5) ? Py : Px) + (size_t)src*DD + p*32;
      #pragma unroll
      for (int i = 0; i < 4; ++i)
        *(bf16x8*)(dp + i*8) = *(const bf16x8*)(sp + i*8);
    }
  }
}

// K5b: reduce per-block partials into stats (few atomics).
__global__ __launch_bounds__(256) void k5b_stats(
    const float* __restrict__ partial, float* __restrict__ stats, int nb)
{
  int seg = blockIdx.y, chunk = blockIdx.x, t = threadIdx.x;
  int per = (nb + gridDim.x - 1) / gridDim.x;
  int lo = chunk*per, hi = lo+per; if (hi > nb) hi = nb;
  float s = 0.f;
  const float* p = partial + (size_t)seg*nb*256;
  for (int i = lo; i < hi; ++i) s += p[(size_t)i*256 + t];
  atomicAdd(&stats[seg*256 + t], s);
}

// K6: BN+PReLU (bf16 P) -> MFMA GEMM2 (+b2, wave-per-column-slice, B-frags
// hoisted) -> parallel per-row BYOL cosine -> 1 atomic/block. NO device fence.
__global__ __launch_bounds__(256) void k6_gemm_loss(
    const u16* __restrict__ Px, const u16* __restrict__ Py,
    const u16* __restrict__ AGGb, const float* __restrict__ stats,
    const float* __restrict__ gamma, const float* __restrict__ beta,
    const float* __restrict__ aP, const u16* __restrict__ W2swz,
    const float* __restrict__ b2, float* __restrict__ gloss, int N)
{
  __shared__ __align__(16) float Cs[64*STRCF];   // 33792B; aliased as As (17408B)
  u16* As = (u16*)Cs;
  __shared__ float s1s[128], s2s[128];
  __shared__ float gred[4];
  const int tid = threadIdx.x;
  const int seg = blockIdx.y;
  const u16* __restrict__ P = seg ? Py : Px;
  const int toff = seg ? 0 : 128;
  const float invN = 1.f / (float)N;
  if (tid < 128) {
    float mu = stats[seg*256 + tid] * invN;
    float var = stats[seg*256 + 128 + tid] * invN - mu*mu;
    float rstd = rsqrtf(var + 1e-5f);
    float s1 = rstd * gamma[tid];
    s1s[tid] = s1;
    s2s[tid] = beta[tid] - mu*s1;
  }
  const float alpha = aP[0];
  const int r0 = blockIdx.x * 64;
  __syncthreads();
  #pragma unroll
  for (int i = 0; i < 4; ++i) {
    int f = tid + 256*i;
    int row = f >> 4, c8 = f & 15;
    int r = r0 + row;
    bf16x8 ch = {0,0,0,0,0,0,0,0};
    if (r < N) ch = *(const bf16x8*)(P + (size_t)r*DD + c8*8);
    bf16x8 a;
    #pragma unroll
    for (int t2 = 0; t2 < 8; ++t2) {
      int colc = c8*8 + t2;
      float hv = bf2f((u16)ch[t2]);
      float hn = hv*s1s[colc] + s2s[colc];
      hn = hn >= 0.f ? hn : alpha*hn;
      a[t2] = (short)f2bf(hn);
    }
    *(bf16x8*)&As[row*STRA + c8*8] = a;
  }
  __syncthreads();
  const int w = tid >> 6, l = tid & 63;
  const int m = l & 15, q = l >> 4;
  const int cbase = w*32 + m;
  f32x4 acc[4][2];
  bf16x8 bfrag[2][4];
  #pragma unroll
  for (int ntl = 0; ntl < 2; ++ntl)
    #pragma unroll
    for (int kt = 0; kt < 4; ++kt)
      bfrag[ntl][kt] = *(const bf16x8*)(W2swz + ((size_t)(kt*8 + w*2 + ntl)*64 + l)*8);
  #pragma unroll
  for (int rt = 0; rt < 4; ++rt) {
    acc[rt][0] = (f32x4){0.f,0.f,0.f,0.f};
    acc[rt][1] = (f32x4){0.f,0.f,0.f,0.f};
  }
  #pragma unroll
  for (int kt = 0; kt < 4; ++kt)
    #pragma unroll
    for (int rt = 0; rt < 4; ++rt) {
      bf16x8 af = *(const bf16x8*)&As[(rt*16 + m)*STRA + kt*32 + q*8];
      acc[rt][0] = __builtin_amdgcn_mfma_f32_16x16x32_bf16(af, bfrag[0][kt], acc[rt][0], 0, 0, 0);
      acc[rt][1] = __builtin_amdgcn_mfma_f32_16x16x32_bf16(af, bfrag[1][kt], acc[rt][1], 0, 0, 0);
    }
  __syncthreads();                  // As dead; Cs writes follow (aliased)
  #pragma unroll
  for (int ntl = 0; ntl < 2; ++ntl) {
    float bv = b2[cbase + ntl*16];
    #pragma unroll
    for (int rt = 0; rt < 4; ++rt)
      #pragma unroll
      for (int i = 0; i < 4; ++i)
        Cs[(rt*16 + q*4 + i)*STRCF + cbase + ntl*16] = acc[rt][ntl][i] + bv;
  }
  __syncthreads();
  // Parallel BYOL cosine: 4 lanes per row; xor1+xor2 completes row sums;
  // xor4..32 sums 16 distinct rows once per qq-group (no /4 — R2 lesson).
  {
    const int rt = tid >> 2, qq = tid & 3;
    const int r = r0 + rt;
    float pp = 0.f, tt = 0.f, pt = 0.f;
    if (r < N) {
      const float* prow = &Cs[rt*STRCF + qq*32];
      const u16* trow = AGGb + (size_t)r*256 + toff + qq*32;
      #pragma unroll
      for (int i = 0; i < 4; ++i) {
        float4 pa = *(const float4*)(prow + i*8);
        float4 pb = *(const float4*)(prow + i*8 + 4);
        uint4 twv = *(const uint4*)(trow + i*8);
        float t0=bflo(twv.x), t1=bfhi(twv.x), t2=bflo(twv.y), t3=bfhi(twv.y);
        float t4=bflo(twv.z), t5=bfhi(twv.z), t6=bflo(twv.w), t7=bfhi(twv.w);
        pp += pa.x*pa.x + pa.y*pa.y + pa.z*pa.z + pa.w*pa.w
            + pb.x*pb.x + pb.y*pb.y + pb.z*pb.z + pb.w*pb.w;
        tt += t0*t0 + t1*t1 + t2*t2 + t3*t3 + t4*t4 + t5*t5 + t6*t6 + t7*t7;
        pt += pa.x*t0 + pa.y*t1 + pa.z*t2 + pa.w*t3
            + pb.x*t4 + pb.y*t5 + pb.z*t6 + pb.w*t7;
      }
    }
    pp += __shfl_xor(pp, 1); pp += __shfl_xor(pp, 2);
    tt += __shfl_xor(tt, 1); tt += __shfl_xor(tt, 2);
    pt += __shfl_xor(pt, 1); pt += __shfl_xor(pt, 2);
    float lsum = (r < N) ? (2.f - 2.f * pt * rsqrtf(pp * tt)) : 0.f;
    lsum += __shfl_xor(lsum, 4);  lsum += __shfl_xor(lsum, 8);
    lsum += __shfl_xor(lsum, 16); lsum += __shfl_xor(lsum, 32);
    if (l == 0) gred[w] = lsum;
  }
  __syncthreads();
  if (tid == 0) atomicAdd(gloss, gred[0]+gred[1]+gred[2]+gred[3]);
}

__global__ void k7_loss(const float* __restrict__ gloss, float* __restrict__ out, int N, int total)
{
  out[total] = gloss[0] / (float)N;
}

extern "C" void kernel_launch(void* const* d_in, const int* in_sizes, int n_in,
                              void* d_out, int out_size, void* d_ws, size_t ws_size,
                              hipStream_t stream)
{
  const float* x    = (const float*)d_in[0];
  const float* perb = (const float*)d_in[1];
  const int*   erow = (const int*)d_in[2];
  const int*   ecol = (const int*)d_in[3];
  const float* eval_= (const float*)d_in[4];
  const float* W    = (const float*)d_in[5];
  const float* b    = (const float*)d_in[6];
  const float* Wt   = (const float*)d_in[7];
  const float* bt   = (const float*)d_in[8];
  const float* W1   = (const float*)d_in[9];
  const float* b1   = (const float*)d_in[10];
  const float* gam  = (const float*)d_in[11];
  const float* bet  = (const float*)d_in[12];
  const float* aP   = (const float*)d_in[13];
  const float* W2   = (const float*)d_in[14];
  const float* b2   = (const float*)d_in[15];
  const int N = in_sizes[0] / DD;
  const int E = in_sizes[2];
  const int NB4 = (N + 31)/32;
  const int NB5 = (N + 63)/64;
  const int rowsPerPart = (N + NPART - 1) / NPART;

  char* ws = (char*)d_ws;
  size_t off = 0;
  auto alloc = [&](size_t bytes) -> void* {
    void* p = ws + off;
    off += (bytes + 255) & ~(size_t)255;
    return p;
  };
  u16*   AGGb = (u16*)  alloc((size_t)N*256*sizeof(u16));   // 25.6 MB [s1|s3]
  u8*    Tg   = (u8*)   alloc((size_t)N*384);               // 19.2 MB gather table
  u16*   T2   = (u16*)  alloc((size_t)N*256*sizeof(u16));   // 25.6 MB
  u16*   Px   = (u16*)  alloc((size_t)N*DD*sizeof(u16));    // 12.8 MB
  u16*   Py   = (u16*)  alloc((size_t)N*DD*sizeof(u16));    // 12.8 MB
  int*   deg  = (int*)  alloc((size_t)N*sizeof(int));
  float* stats= (float*)alloc(512*sizeof(float));
  float* gloss= (float*)alloc(256);
  int*   ovfc = (int*)((char*)gloss + 64);
  u32*   perm = (u32*)  alloc((size_t)N*CAP*sizeof(u32));   // 12.8 MB packed
  int*   ovf  = (int*)  alloc(4096*sizeof(int));
  u16*   Bswz = (u16*)  alloc(32768*sizeof(u16));
  u16*   W1swz= (u16*)  alloc(16384*sizeof(u16));
  u16*   W2swz= (u16*)  alloc(16384*sizeof(u16));
  float* partial = (float*)alloc((size_t)2*NB4*256*sizeof(float)); // 3.2 MB
  if (ws_size < off) return;

  kU_init<<<(N*32 + 255)/256, 256, 0, stream>>>(x, perb, W, Wt, W1, W2,
                                                Tg, Bswz, W1swz, W2swz,
                                                deg, stats, gloss, N);
  k2_bucket<<<2048, 256, 0, stream>>>(erow, ecol, eval_, E, deg, perm, ovfc, ovf,
                                      rowsPerPart);
  k3_spmm<<<(N + 3)/4, 256, 0, stream>>>(perm, deg, Tg, T2, N);
  k3b_ovf<<<1, 256, 0, stream>>>(erow, ecol, eval_, ovfc, ovf, Tg, T2);
  k4_gemm<<<NB4, 256, 0, stream>>>(T2, Bswz, W1swz, b, bt, b1, Tg,
                                   AGGb, (float*)d_out, Px, Py, partial, N, NB4);
  k5b_stats<<<dim3(16, 2), 256, 0, stream>>>(partial, stats, NB4);
  k6_gemm_loss<<<dim3(NB5, 2), 256, 0, stream>>>(Px, Py, AGGb, stats, gam, bet, aP,
                                                 W2swz, b2, gloss, N);
  k7_loss<<<1, 1, 0, stream>>>(gloss, (float*)d_out, N, N*DD);
}